// Round 2
// baseline (747.744 us; speedup 1.0000x reference)
//
#include <hip/hip_runtime.h>
#include <stdint.h>

// ---------------------------------------------------------------------------
// TimeAwareIMULSTMEncoder on MI355X (gfx950) — round 2
// Key changes vs round 1:
//  * xg layout gate-packed: [dir][t][seq][hcol*4+gate] (bf16) so the scan
//    reads per-lane gate quads as one ds_read_b64.
//  * k_xg_gemm: 128x512 block tile (all 4 gates in-block), 512 thr, packed
//    8B coalesced epilogue stores, register-double-buffered staging.
//  * k_scan: 512 thr / 8 waves; x staged via __builtin_amdgcn_global_load_lds
//    (double-buffered 16KB/step); Whh^T frags in VGPRs; pointwise in-register;
//    pending Y stores flushed next step (hides store ack before barrier);
//    layer 2 fuses mean/max/final aggregation (k_agg deleted).
// ---------------------------------------------------------------------------

typedef unsigned short ushort_t;
typedef short short8 __attribute__((ext_vector_type(8)));     // 8 bf16 (4 VGPRs)
typedef float float4v __attribute__((ext_vector_type(4)));    // MFMA acc
typedef unsigned short ushort4v __attribute__((ext_vector_type(4)));

#define DEV_INLINE __device__ __forceinline__

DEV_INLINE ushort_t f2bf(float f) {                 // RNE f32 -> bf16 bits
  union { float f; unsigned u; } v; v.f = f;
  unsigned r = v.u + 0x7fffu + ((v.u >> 16) & 1u);
  return (ushort_t)(r >> 16);
}
DEV_INLINE float bf2f(ushort_t s) {
  union { unsigned u; float f; } v; v.u = ((unsigned)s) << 16;
  return v.f;
}
DEV_INLINE float sigmoidf_(float x) {
  return __builtin_amdgcn_rcpf(1.0f + __expf(-x));
}
DEV_INLINE float tanhf_(float x) {                  // 1 - 2/(1+e^{2x}); safe at +-inf
  return 1.0f - 2.0f * __builtin_amdgcn_rcpf(1.0f + __expf(2.0f * x));
}

// async global->LDS: each lane fetches 16B from its own address; LDS dest is
// wave-uniform base + lane*16 (m97-verified pattern).
DEV_INLINE void gload16(const ushort_t* g, ushort_t* l) {
  __builtin_amdgcn_global_load_lds(
      (const __attribute__((address_space(1))) unsigned int*)g,
      (__attribute__((address_space(3))) unsigned int*)l, 16, 0, 0);
}

// --------------------------- weight prep -----------------------------------
// WT arena (elements): Wih0[2*512*64] | Wih1[2*512*256] | Wih2[2*512*256]
//                    | Whh0[2*512*128] | Whh1[2*512*128] | Whh2[2*512*128]
__global__ __launch_bounds__(256) void k_prep(
    const float* __restrict__ Wih0, const float* __restrict__ Wih1,
    const float* __restrict__ Wih2, const float* __restrict__ Whh0,
    const float* __restrict__ Whh1, const float* __restrict__ Whh2,
    ushort_t* __restrict__ WT)
{
  int idx = blockIdx.x * 256 + threadIdx.x;
  const float* src; int K, klog, base;
  if      (idx < 65536)  { src = Wih0; K = 64;  klog = 6; base = 0; }
  else if (idx < 327680) { src = Wih1; K = 256; klog = 8; base = 65536; }
  else if (idx < 589824) { src = Wih2; K = 256; klog = 8; base = 327680; }
  else if (idx < 720896) { src = Whh0; K = 128; klog = 7; base = 589824; }
  else if (idx < 851968) { src = Whh1; K = 128; klog = 7; base = 720896; }
  else if (idx < 983040) { src = Whh2; K = 128; klog = 7; base = 851968; }
  else return;
  int li = idx - base;
  int k = li & (K - 1);
  int nd = li >> klog;
  int n = nd & 511, d = nd >> 9;
  WT[idx] = f2bf(src[(size_t)(d * K + k) * 512 + n]);
}

// --------------------------- input projection ------------------------------
__global__ __launch_bounds__(256) void k_inproj(
    const float* __restrict__ imu, const float* __restrict__ W_in,
    const float* __restrict__ b_in, ushort_t* __restrict__ act0)
{
  int idx = blockIdx.x * 256 + threadIdx.x;   // 64000*64 exactly
  int j = idx & 63, r = idx >> 6;
  int l = r % 50;
  const float* x = imu + (size_t)r * 6;
  float acc = b_in[j];
#pragma unroll
  for (int d = 0; d < 6; d++) acc += x[d] * W_in[d * 64 + j];
  acc += (l * (1.0f / 49.0f)) * W_in[6 * 64 + j] + W_in[7 * 64 + j]; // t, rate=1
  act0[idx] = f2bf(fmaxf(acc, 0.0f));
}

// --------------------------- xg GEMM (bf16 MFMA, 128x512 tile) --------------
// xg[dirSlot][t][seq][hcol*4+g] = X[m][:] @ Wih[dir][:][g*128+hcol] + bias
// Block: 512 thr (8 waves). Wave w owns hcols [w*16, w*16+16) across all 4
// gates -> each lane holds the 4 gate values of its (row,hcol) -> 8B packed
// coalesced store. Staging reg-double-buffered; prefetch issued after the
// "LDS ready" barrier so its latency hides under the MFMA phase.
template <int K>
__global__ __launch_bounds__(512, 1) void k_xg_gemm(
    const ushort_t* __restrict__ X,    // [64000][K] bf16 (m-major)
    const ushort_t* __restrict__ WT,   // [2][512][K] bf16 (n-major)
    const float* __restrict__ bih, const float* __restrict__ bhh, // [2][512]
    ushort_t* __restrict__ xg,         // [gridDim.z][50][1280][512]
    int dirBase)
{
  constexpr int LDK = 40;              // 32 + 8 pad (80B rows, 16B aligned)
  __shared__ __align__(16) ushort_t As[128 * LDK];   // 10.0 KiB
  __shared__ __align__(16) ushort_t Bs[512 * LDK];   // 40.0 KiB
  const int dir = blockIdx.z + dirBase;
  const int m0 = blockIdx.x * 128;
  const int tid = threadIdx.x;
  const int wave = tid >> 6, lane = tid & 63;
  const int cl = lane & 15, quad = lane >> 4;
  const ushort_t* Wd = WT + (size_t)dir * 512 * K;

  float4v acc[8][4];
#pragma unroll
  for (int i = 0; i < 8; i++)
#pragma unroll
    for (int g = 0; g < 4; g++) acc[i][g] = float4v{0.f, 0.f, 0.f, 0.f};

  const int ar = tid >> 2;             // A stage: row 0..127
  const int ac = (tid & 3) * 8;        //          col-ushort 0/8/16/24

  uint4 pa;
  uint4 pb[4];
  pa = *(const uint4*)(X + (size_t)(m0 + ar) * K + ac);
#pragma unroll
  for (int c = 0; c < 4; c++)
    pb[c] = *(const uint4*)(Wd + (size_t)tid * K + c * 8);

  for (int kb = 0; kb < K; kb += 32) {
    if (kb) __syncthreads();           // LDS consumed by previous MFMA phase
    *(uint4*)(&As[ar * LDK + ac]) = pa;
#pragma unroll
    for (int c = 0; c < 4; c++)
      *(uint4*)(&Bs[tid * LDK + c * 8]) = pb[c];
    __syncthreads();                   // LDS ready (nothing outstanding)
    if (kb + 32 < K) {                 // prefetch next kb; hides under MFMA
      pa = *(const uint4*)(X + (size_t)(m0 + ar) * K + kb + 32 + ac);
#pragma unroll
      for (int c = 0; c < 4; c++)
        pb[c] = *(const uint4*)(Wd + (size_t)tid * K + kb + 32 + c * 8);
    }
    short8 Bf[4];
#pragma unroll
    for (int g = 0; g < 4; g++)
      Bf[g] = *(const short8*)(&Bs[(g * 128 + wave * 16 + cl) * LDK + quad * 8]);
#pragma unroll
    for (int i = 0; i < 8; i++) {
      short8 Af = *(const short8*)(&As[(i * 16 + cl) * LDK + quad * 8]);
#pragma unroll
      for (int g = 0; g < 4; g++)
        acc[i][g] = __builtin_amdgcn_mfma_f32_16x16x32_bf16(Af, Bf[g], acc[i][g], 0, 0, 0);
    }
  }

  // epilogue: pack 4 gates -> 8B store; lanes cl 0..15 -> 128B contiguous
  const int hcol = wave * 16 + cl;
  float bb[4];
#pragma unroll
  for (int g = 0; g < 4; g++)
    bb[g] = bih[dir * 512 + g * 128 + hcol] + bhh[dir * 512 + g * 128 + hcol];
  ushort_t* outp = xg + (size_t)blockIdx.z * (50ull * 1280 * 512);
#pragma unroll
  for (int i = 0; i < 8; i++) {
#pragma unroll
    for (int r = 0; r < 4; r++) {
      int m = m0 + i * 16 + quad * 4 + r;
      int seq = m / 50, t = m - seq * 50;
      unsigned lo = (unsigned)f2bf(acc[i][0][r] + bb[0]) |
                    ((unsigned)f2bf(acc[i][1][r] + bb[1]) << 16);
      unsigned hi = (unsigned)f2bf(acc[i][2][r] + bb[2]) |
                    ((unsigned)f2bf(acc[i][3][r] + bb[3]) << 16);
      uint2 pk; pk.x = lo; pk.y = hi;
      *(uint2*)(outp + ((size_t)t * 1280 + seq) * 512 + hcol * 4) = pk;
    }
  }
}

// --------------------------- LSTM scan -------------------------------------
// One block = 16 sequences of one direction, 50 steps, 512 thr (8 waves).
// Wave w owns hcols [w*16,w*16+16): Bf[gate][kt] in VGPRs (64 VGPRs).
// x gates staged per-step into double-buffered LDS via global_load_lds.
// MODE 0: write Y (bf16, m-major). MODE 1: fused mean/max/final aggregation.
template <int MODE>
__global__ __launch_bounds__(512, 1) void k_scan(
    const ushort_t* __restrict__ xg,    // [gridDim.y][50][1280][512] packed
    const ushort_t* __restrict__ WhhT,  // [2][512][128] bf16 n-major
    ushort_t* __restrict__ Y,           // [64000][256] bf16
    float* __restrict__ agg,            // [1280][768] f32
    int dirBase)
{
  const int dir = blockIdx.y + dirBase;
  const int s0 = blockIdx.x * 16;
  const int tid = threadIdx.x;
  const int wave = tid >> 6, lane = tid & 63;
  const int cl = lane & 15, quad = lane >> 4;
  const int hcol = wave * 16 + cl;

  __shared__ __align__(16) ushort_t xbuf[2][16 * 512];   // 32 KiB, rows 1KiB
  __shared__ __align__(16) ushort_t hbuf[2][16][136];    // 8.5 KiB

  // Whh^T fragments: n = g*128 + hcol, k = kt*32 + quad*8
  short8 Bf[4][4];
  const ushort_t* WTd = WhhT + (size_t)dir * (512 * 128);
#pragma unroll
  for (int g = 0; g < 4; g++)
#pragma unroll
    for (int kt = 0; kt < 4; kt++)
      Bf[g][kt] = *(const short8*)(WTd + (g * 128 + hcol) * 128 + kt * 32 + quad * 8);

  float cst[4] = {0.f, 0.f, 0.f, 0.f};
  float sum[4] = {0.f, 0.f, 0.f, 0.f};
  float mx[4]  = {-3.0e38f, -3.0e38f, -3.0e38f, -3.0e38f};
  float hLast[4] = {0.f, 0.f, 0.f, 0.f};
  ushort_t pend[4] = {0, 0, 0, 0};
  int tPrev = 0;

  for (int i = tid; i < 16 * 136; i += 512) ((ushort_t*)hbuf[0])[i] = 0;

  const ushort_t* xgp = xg + (size_t)blockIdx.y * (50ull * 1280 * 512);
  const int t0 = dir ? 49 : 0;
  {
    const ushort_t* src = xgp + ((size_t)t0 * 1280 + s0) * 512 + wave * 1024 + lane * 8;
    ushort_t* dst = &xbuf[0][wave * 1024];
    gload16(src, dst);
    gload16(src + 512, dst + 512);
  }
  __syncthreads();   // drains the prologue copy

  for (int step = 0; step < 50; step++) {
    const int t = dir ? (49 - step) : step;
    const int cur = step & 1;

    if (step < 49) {                    // prefetch next step's x into other buf
      const int tn = dir ? (t - 1) : (t + 1);
      const ushort_t* src = xgp + ((size_t)tn * 1280 + s0) * 512 + wave * 1024 + lane * 8;
      ushort_t* dst = &xbuf[cur ^ 1][wave * 1024];
      gload16(src, dst);
      gload16(src + 512, dst + 512);
    }
    if (MODE == 0 && step > 0) {        // flush previous step's Y (full step to retire)
#pragma unroll
      for (int r = 0; r < 4; r++)
        Y[((size_t)(s0 + quad * 4 + r) * 50 + tPrev) * 256 + dir * 128 + hcol] = pend[r];
    }

    short8 Af[4];
#pragma unroll
    for (int kt = 0; kt < 4; kt++)      // A: m=lane&15, k=quad*8+j
      Af[kt] = *(const short8*)(&hbuf[cur][cl][kt * 32 + quad * 8]);

    float4v acc[4];
#pragma unroll
    for (int g = 0; g < 4; g++) acc[g] = float4v{0.f, 0.f, 0.f, 0.f};
#pragma unroll
    for (int kt = 0; kt < 4; kt++)
#pragma unroll
      for (int g = 0; g < 4; g++)
        acc[g] = __builtin_amdgcn_mfma_f32_16x16x32_bf16(Af[kt], Bf[g][kt], acc[g], 0, 0, 0);

#pragma unroll
    for (int r = 0; r < 4; r++) {
      const int seq = quad * 4 + r;
      ushort4v xq = *(const ushort4v*)(&xbuf[cur][seq * 512 + hcol * 4]);
      float gi = acc[0][r] + bf2f(xq.x);
      float gf = acc[1][r] + bf2f(xq.y);
      float gg = acc[2][r] + bf2f(xq.z);
      float go = acc[3][r] + bf2f(xq.w);
      float ii = sigmoidf_(gi);
      float ff = sigmoidf_(gf);
      float gc = tanhf_(gg);
      float oo = sigmoidf_(go);
      float c = ff * cst[r] + ii * gc;
      cst[r] = c;
      float h = oo * tanhf_(c);
      ushort_t hb = f2bf(h);
      hbuf[cur ^ 1][seq][hcol] = hb;
      if (MODE == 0) {
        pend[r] = hb;
      } else {
        sum[r] += h;
        mx[r] = fmaxf(mx[r], h);
        hLast[r] = h;
      }
    }
    tPrev = t;
    __syncthreads();
  }

  if (MODE == 0) {
#pragma unroll
    for (int r = 0; r < 4; r++)
      Y[((size_t)(s0 + quad * 4 + r) * 50 + tPrev) * 256 + dir * 128 + hcol] = pend[r];
  } else {
#pragma unroll
    for (int r = 0; r < 4; r++) {
      const int seq = s0 + quad * 4 + r;
      const int c = dir * 128 + hcol;
      agg[(size_t)seq * 768 + c] = sum[r] * (1.0f / 50.0f);
      agg[(size_t)seq * 768 + 256 + c] = mx[r];
      agg[(size_t)seq * 768 + 512 + c] = hLast[r];   // h_n of this direction
    }
  }
}

// --------------------------- head: GEMM1 (fp32) -----------------------------
__global__ __launch_bounds__(256) void k_head1(
    const float* __restrict__ agg, const float* __restrict__ W1,
    const float* __restrict__ b1, float* __restrict__ h1)
{
  __shared__ float aggS[16][772];
  const int n0 = blockIdx.x * 16;
  const int c0 = blockIdx.y * 128;
  const int tid = threadIdx.x;
  for (int i = tid; i < 16 * 192; i += 256) {
    int row = i / 192, c4 = i % 192;
    *(float4v*)(&aggS[row][c4 * 4]) =
        *(const float4v*)(agg + (size_t)(n0 + row) * 768 + c4 * 4);
  }
  __syncthreads();
  const int cq = tid & 31;          // cols c0 + cq*4 .. +3
  const int rp = tid >> 5;          // rows rp*2, rp*2+1
  float acc0[4] = {0.f, 0.f, 0.f, 0.f}, acc1[4] = {0.f, 0.f, 0.f, 0.f};
#pragma unroll 4
  for (int k = 0; k < 768; k++) {
    float4v w = *(const float4v*)(W1 + (size_t)k * 512 + c0 + cq * 4);
    float a0 = aggS[rp * 2][k], a1 = aggS[rp * 2 + 1][k];
#pragma unroll
    for (int q = 0; q < 4; q++) { acc0[q] += a0 * w[q]; acc1[q] += a1 * w[q]; }
  }
#pragma unroll
  for (int q = 0; q < 4; q++) {
    int col = c0 + cq * 4 + q;
    float bb = b1[col];
    h1[(size_t)(n0 + rp * 2) * 512 + col] = acc0[q] + bb;
    h1[(size_t)(n0 + rp * 2 + 1) * 512 + col] = acc1[q] + bb;
  }
}

// --------------------------- head: LN + relu + GEMM2 (fp32) -----------------
__global__ __launch_bounds__(256) void k_head2(
    const float* __restrict__ h1, const float* __restrict__ ln_g,
    const float* __restrict__ ln_b, const float* __restrict__ W2,
    const float* __restrict__ b2, float* __restrict__ out)
{
  __shared__ float hnS[8][516];
  const int n0 = blockIdx.x * 8;
  const int tid = threadIdx.x;
  const int row = tid >> 5, li = tid & 31;
  const float* hr = h1 + (size_t)(n0 + row) * 512;
  float sum = 0.f, sq = 0.f;
  float v[16];
#pragma unroll
  for (int j = 0; j < 16; j++) {
    v[j] = hr[li + 32 * j];
    sum += v[j]; sq += v[j] * v[j];
  }
#pragma unroll
  for (int m = 1; m <= 16; m <<= 1) {
    sum += __shfl_xor(sum, m);
    sq  += __shfl_xor(sq, m);
  }
  float mu = sum * (1.0f / 512.0f);
  float var = sq * (1.0f / 512.0f) - mu * mu;
  float rs = rsqrtf(var + 1e-5f);
#pragma unroll
  for (int j = 0; j < 16; j++) {
    int col = li + 32 * j;
    float y = (v[j] - mu) * rs * ln_g[col] + ln_b[col];
    hnS[row][col] = fmaxf(y, 0.0f);
  }
  __syncthreads();
  const int cq = tid & 63, rp = tid >> 6;   // cols cq*4..+3; rows rp*2, rp*2+1
  float acc0[4] = {0.f, 0.f, 0.f, 0.f}, acc1[4] = {0.f, 0.f, 0.f, 0.f};
#pragma unroll 4
  for (int k = 0; k < 512; k++) {
    float4v w = *(const float4v*)(W2 + (size_t)k * 256 + cq * 4);
    float a0 = hnS[rp * 2][k], a1 = hnS[rp * 2 + 1][k];
#pragma unroll
    for (int q = 0; q < 4; q++) { acc0[q] += a0 * w[q]; acc1[q] += a1 * w[q]; }
  }
#pragma unroll
  for (int q = 0; q < 4; q++) {
    int col = cq * 4 + q;
    float bb = b2[col];
    out[(size_t)(n0 + rp * 2) * 256 + col] = acc0[q] + bb;
    out[(size_t)(n0 + rp * 2 + 1) * 256 + col] = acc1[q] + bb;
  }
}

// --------------------------- launcher --------------------------------------
extern "C" void kernel_launch(void* const* d_in, const int* in_sizes, int n_in,
                              void* d_out, int out_size, void* d_ws, size_t ws_size,
                              hipStream_t stream)
{
  (void)in_sizes; (void)n_in; (void)out_size;
  const float* imu   = (const float*)d_in[0];
  const float* W_in  = (const float*)d_in[1];
  const float* b_in  = (const float*)d_in[2];
  const float* Wih0  = (const float*)d_in[3];
  const float* Whh0  = (const float*)d_in[4];
  const float* bih0  = (const float*)d_in[5];
  const float* bhh0  = (const float*)d_in[6];
  const float* Wih1  = (const float*)d_in[7];
  const float* Whh1  = (const float*)d_in[8];
  const float* bih1  = (const float*)d_in[9];
  const float* bhh1  = (const float*)d_in[10];
  const float* Wih2  = (const float*)d_in[11];
  const float* Whh2  = (const float*)d_in[12];
  const float* bih2  = (const float*)d_in[13];
  const float* bhh2  = (const float*)d_in[14];
  const float* Wout1 = (const float*)d_in[15];
  const float* bout1 = (const float*)d_in[16];
  const float* ln_g  = (const float*)d_in[17];
  const float* ln_b  = (const float*)d_in[18];
  const float* Wout2 = (const float*)d_in[19];
  const float* bout2 = (const float*)d_in[20];
  float* out = (float*)d_out;
  char* ws = (char*)d_ws;

  // ws layout (bytes)
  const size_t ACT0_OFF = 0;                      // 8,192,000  (64000*64*2)
  const size_t YA_OFF   = 8192000;                // 32,768,000 (64000*256*2)
  const size_t YB_OFF   = 40960000;               // 32,768,000
  const size_t XG_OFF   = 73728000;               // 131,072,000 (both) / 65,536,000 (serial)
  const size_t XG_BOTH  = 131072000, XG_SER = 65536000;
  const size_t WT_SZ    = 1966080;                // 983,040 bf16 elems
  const bool both = ws_size >= XG_OFF + XG_BOTH + WT_SZ;
  const size_t WT_OFF = XG_OFF + (both ? XG_BOTH : XG_SER);

  ushort_t* act0 = (ushort_t*)(ws + ACT0_OFF);
  ushort_t* Ya   = (ushort_t*)(ws + YA_OFF);
  ushort_t* Yb   = (ushort_t*)(ws + YB_OFF);
  ushort_t* xg   = (ushort_t*)(ws + XG_OFF);
  ushort_t* WT   = (ushort_t*)(ws + WT_OFF);
  float* agg = (float*)(ws + 0);                  // reuses act0 region (dead by then)
  float* h1  = (float*)(ws + 4194304);

  ushort_t* WT_ih0 = WT + 0;
  ushort_t* WT_ih1 = WT + 65536;
  ushort_t* WT_ih2 = WT + 327680;
  ushort_t* WT_hh0 = WT + 589824;
  ushort_t* WT_hh1 = WT + 720896;
  ushort_t* WT_hh2 = WT + 851968;

  k_prep<<<3840, 256, 0, stream>>>(Wih0, Wih1, Wih2, Whh0, Whh1, Whh2, WT);
  k_inproj<<<16000, 256, 0, stream>>>(imu, W_in, b_in, act0);

  const int nPass = both ? 1 : 2;
  const int gz = both ? 2 : 1;

  const ushort_t* Xs[3]   = {act0, Ya, Yb};
  ushort_t* Ys[3]         = {Ya, Yb, Ya};
  const ushort_t* WTih[3] = {WT_ih0, WT_ih1, WT_ih2};
  const ushort_t* WThh[3] = {WT_hh0, WT_hh1, WT_hh2};
  const float* bihs[3]    = {bih0, bih1, bih2};
  const float* bhhs[3]    = {bhh0, bhh1, bhh2};

  for (int layer = 0; layer < 3; layer++) {
    for (int p = 0; p < nPass; p++) {
      int dirBase = both ? 0 : p;
      if (layer == 0)
        k_xg_gemm<64><<<dim3(500, 1, gz), 512, 0, stream>>>(
            Xs[0], WTih[0], bihs[0], bhhs[0], xg, dirBase);
      else
        k_xg_gemm<256><<<dim3(500, 1, gz), 512, 0, stream>>>(
            Xs[layer], WTih[layer], bihs[layer], bhhs[layer], xg, dirBase);
      if (layer < 2)
        k_scan<0><<<dim3(80, gz), 512, 0, stream>>>(xg, WThh[layer], Ys[layer], agg, dirBase);
      else
        k_scan<1><<<dim3(80, gz), 512, 0, stream>>>(xg, WThh[layer], Ys[layer], agg, dirBase);
    }
  }

  k_head1<<<dim3(80, 4), 256, 0, stream>>>(agg, Wout1, bout1, h1);
  k_head2<<<160, 256, 0, stream>>>(h1, ln_g, ln_b, Wout2, bout2, out);
}

// Round 3
// 585.711 us; speedup vs baseline: 1.2766x; 1.2766x over previous
//
#include <hip/hip_runtime.h>
#include <stdint.h>

// ---------------------------------------------------------------------------
// TimeAwareIMULSTMEncoder on MI355X (gfx950) — round 3
// vs round 2:
//  * xg split into 2 gate-pair planes: [dir][gp][t][seq][hc*2+q] (gp0=i,f;
//    gp1=g,o). GEMM tile shrinks to M=64 x N=256 (acc = 64 AGPR/wave, was 128)
//    -> 3-4 blocks/CU instead of 1 (round-2 GEMM was occupancy-strangled:
//    21% occ, all pipes <25%).
//  * GEMM staging via global_load_lds (width 16), LDS double-buffered,
//    one barrier per K-iter, unpadded lane-contiguous LDS (DMA rule).
//  * k_prep rewritten as LDS tile transpose (old: stride-2KB reads, 16x
//    fetch amplification).
//  * scan: reads (i,f)/(g,o) as 2 x b32 from the two planes; otherwise as r2.
// ---------------------------------------------------------------------------

typedef unsigned short ushort_t;
typedef short short8 __attribute__((ext_vector_type(8)));     // 8 bf16 (4 VGPRs)
typedef float float4v __attribute__((ext_vector_type(4)));    // MFMA acc

#define DEV_INLINE __device__ __forceinline__

DEV_INLINE ushort_t f2bf(float f) {                 // RNE f32 -> bf16 bits
  union { float f; unsigned u; } v; v.f = f;
  unsigned r = v.u + 0x7fffu + ((v.u >> 16) & 1u);
  return (ushort_t)(r >> 16);
}
DEV_INLINE float bf2f(ushort_t s) {
  union { unsigned u; float f; } v; v.u = ((unsigned)s) << 16;
  return v.f;
}
DEV_INLINE float sigmoidf_(float x) {
  return __builtin_amdgcn_rcpf(1.0f + __expf(-x));
}
DEV_INLINE float tanhf_(float x) {                  // 1 - 2/(1+e^{2x}); safe at +-inf
  return 1.0f - 2.0f * __builtin_amdgcn_rcpf(1.0f + __expf(2.0f * x));
}

// async global->LDS, 16B per lane; dst must be wave-uniform base + lane*16.
DEV_INLINE void gload16(const ushort_t* g, ushort_t* l) {
  __builtin_amdgcn_global_load_lds(
      (const __attribute__((address_space(1))) unsigned int*)g,
      (__attribute__((address_space(3))) unsigned int*)l, 16, 0, 0);
}

// --------------------------- weight prep (tiled transpose) ------------------
// src tensors [2][K][512] f32 -> WT [2][512][K] bf16.
// Tile = 32 k x 64 n via LDS; coalesced reads (256B/row) and writes (16B/thr).
struct PrepDesc { const float* src; int K; int base; int firstBlk; };

__global__ __launch_bounds__(256) void k_prep(
    const float* __restrict__ Wih0, const float* __restrict__ Wih1,
    const float* __restrict__ Wih2, const float* __restrict__ Whh0,
    const float* __restrict__ Whh1, const float* __restrict__ Whh2,
    ushort_t* __restrict__ WT)
{
  __shared__ float T[32][65];
  int b = blockIdx.x;
  const float* src; int K, base, rel;
  // tiles per tensor: 2 * (K/32) * 8
  if      (b < 32)  { src = Wih0; K = 64;  base = 0;      rel = b; }
  else if (b < 160) { src = Wih1; K = 256; base = 65536;  rel = b - 32; }
  else if (b < 288) { src = Wih2; K = 256; base = 327680; rel = b - 160; }
  else if (b < 352) { src = Whh0; K = 128; base = 589824; rel = b - 288; }
  else if (b < 416) { src = Whh1; K = 128; base = 720896; rel = b - 352; }
  else              { src = Whh2; K = 128; base = 851968; rel = b - 416; }
  const int ktiles = K >> 5;
  const int nt = rel & 7;             // 8 n-tiles of 64
  const int kt = (rel >> 3) % ktiles;
  const int d  = (rel >> 3) / ktiles;
  const int k0 = kt * 32, n0 = nt * 64;
  const int tid = threadIdx.x;

  // read: 32 rows of 64 floats, coalesced
  {
    int kr = tid >> 6;                // 0..3
    int n  = tid & 63;
#pragma unroll
    for (int i = 0; i < 8; i++) {
      int k = i * 4 + kr;
      T[k][n] = src[((size_t)d * K + k0 + k) * 512 + n0 + n];
    }
  }
  __syncthreads();
  // write: each thread emits 8 bf16 (16B) along k for one n
  {
    int n = tid >> 2;                 // 0..63
    int ko = (tid & 3) * 8;           // 0,8,16,24
    ushort_t pk[8];
#pragma unroll
    for (int j = 0; j < 8; j++) pk[j] = f2bf(T[ko + j][n]);
    *(uint4*)(WT + base + ((size_t)d * 512 + n0 + n) * K + k0 + ko) = *(uint4*)pk;
  }
}

// --------------------------- input projection ------------------------------
__global__ __launch_bounds__(256) void k_inproj(
    const float* __restrict__ imu, const float* __restrict__ W_in,
    const float* __restrict__ b_in, ushort_t* __restrict__ act0)
{
  int idx = blockIdx.x * 256 + threadIdx.x;   // 64000*64 exactly
  int j = idx & 63, r = idx >> 6;
  int l = r % 50;
  const float* x = imu + (size_t)r * 6;
  float acc = b_in[j];
#pragma unroll
  for (int d = 0; d < 6; d++) acc += x[d] * W_in[d * 64 + j];
  acc += (l * (1.0f / 49.0f)) * W_in[6 * 64 + j] + W_in[7 * 64 + j]; // t, rate=1
  act0[idx] = f2bf(fmaxf(acc, 0.0f));
}

// --------------------------- xg GEMM (bf16 MFMA, 64x256 tile) ---------------
// Grid: (1000 m-tiles, 2 gate-pairs, dirs). Block 256 thr / 4 waves.
// Wave w owns hcols w*32 + u*16 + cl (u 0/1) for both gates of the pair.
// acc[4 m][2 u][2 q] = 16 float4v = 64 AGPR. A/B staged by global_load_lds
// into double-buffered unpadded LDS; one barrier per K-iter.
template <int K>
__global__ __launch_bounds__(256, 3) void k_xg_gemm(
    const ushort_t* __restrict__ X,    // [64000][K] bf16 (m-major)
    const ushort_t* __restrict__ WT,   // [2][512][K] bf16 (n-major)
    const float* __restrict__ bih, const float* __restrict__ bhh, // [2][512]
    ushort_t* __restrict__ xg,         // [dirSlot][2][50][1280][256]
    int dirBase)
{
  __shared__ __align__(16) ushort_t As[2][64 * 32];    //  8 KiB
  __shared__ __align__(16) ushort_t Bs[2][256 * 32];   // 32 KiB
  const int dir = blockIdx.z + dirBase;
  const int gp  = blockIdx.y;
  const int m0  = blockIdx.x * 64;
  const int tid = threadIdx.x;
  const int wave = tid >> 6, lane = tid & 63;
  const int cl = lane & 15, quad = lane >> 4;
  const ushort_t* Wd = WT + ((size_t)dir * 512 + gp * 256) * K;   // 256 rows

  float4v acc[4][2][2];
#pragma unroll
  for (int i = 0; i < 4; i++)
#pragma unroll
    for (int u = 0; u < 2; u++)
#pragma unroll
      for (int q = 0; q < 2; q++) acc[i][u][q] = float4v{0.f, 0.f, 0.f, 0.f};

  // per-lane DMA source offsets (row = >>2 within 16-row group, 8-ushort col)
  const int srow = lane >> 2;         // 0..15
  const int scol = (lane & 3) * 8;    // 0,8,16,24

  // stage(kb -> buf): A 64x32 (1 instr/wave), B 256x32 (4 instr/wave)
#define STAGE(buf, kb)                                                        \
  {                                                                           \
    gload16(X + (size_t)(m0 + wave * 16 + srow) * K + (kb) + scol,            \
            &As[buf][wave * 16 * 32] + lane * 8);                             \
    _Pragma("unroll")                                                         \
    for (int j = 0; j < 4; j++)                                               \
      gload16(Wd + (size_t)(wave * 64 + j * 16 + srow) * K + (kb) + scol,     \
              &Bs[buf][(wave * 64 + j * 16) * 32] + lane * 8);                \
  }

  STAGE(0, 0)
  for (int kb = 0; kb < K; kb += 32) {
    const int cur = (kb >> 5) & 1;
    __syncthreads();                  // drains DMA for cur; protects cur^1 reuse
    if (kb + 32 < K) STAGE(cur ^ 1, kb + 32)
    short8 Af[4], Bf[2][2];
#pragma unroll
    for (int i = 0; i < 4; i++)
      Af[i] = *(const short8*)(&As[cur][(i * 16 + cl) * 32 + quad * 8]);
#pragma unroll
    for (int u = 0; u < 2; u++)
#pragma unroll
      for (int q = 0; q < 2; q++)
        Bf[u][q] = *(const short8*)(&Bs[cur][(q * 128 + wave * 32 + u * 16 + cl) * 32 + quad * 8]);
#pragma unroll
    for (int i = 0; i < 4; i++)
#pragma unroll
      for (int u = 0; u < 2; u++)
#pragma unroll
        for (int q = 0; q < 2; q++)
          acc[i][u][q] = __builtin_amdgcn_mfma_f32_16x16x32_bf16(Af[i], Bf[u][q], acc[i][u][q], 0, 0, 0);
  }
#undef STAGE

  // epilogue: pack gate pair -> 4B store; lanes cl 0..15 -> 64B contiguous
  ushort_t* outp = xg + (size_t)blockIdx.z * 32768000ull + (size_t)gp * 16384000ull;
  const int gbase = dir * 512 + gp * 256;
#pragma unroll
  for (int u = 0; u < 2; u++) {
    const int hc = wave * 32 + u * 16 + cl;
    float b0 = bih[gbase + hc] + bhh[gbase + hc];
    float b1 = bih[gbase + 128 + hc] + bhh[gbase + 128 + hc];
#pragma unroll
    for (int i = 0; i < 4; i++) {
#pragma unroll
      for (int r = 0; r < 4; r++) {
        int m = m0 + i * 16 + quad * 4 + r;   // D: row=quad*4+r, col=lane&15
        int seq = m / 50, t = m - seq * 50;
        unsigned pk = (unsigned)f2bf(acc[i][u][0][r] + b0) |
                      ((unsigned)f2bf(acc[i][u][1][r] + b1) << 16);
        *(unsigned*)(outp + ((size_t)t * 1280 + seq) * 256 + hc * 2) = pk;
      }
    }
  }
}

// --------------------------- LSTM scan -------------------------------------
// One block = 16 sequences of one direction, 50 steps, 512 thr (8 waves).
// Wave w owns hcols w*16..w*16+15; Bf[gate][kt] in VGPRs (64 VGPRs).
// x gates staged per-step into double-buffered LDS via global_load_lds
// (two gate-pair planes). MODE 0: write Y. MODE 1: fused aggregation.
template <int MODE>
__global__ __launch_bounds__(512, 1) void k_scan(
    const ushort_t* __restrict__ xg,    // [dirSlot][2][50][1280][256]
    const ushort_t* __restrict__ WhhT,  // [2][512][128] bf16 n-major
    ushort_t* __restrict__ Y,           // [64000][256] bf16
    float* __restrict__ agg,            // [1280][768] f32
    int dirBase)
{
  const int dir = blockIdx.y + dirBase;
  const int s0 = blockIdx.x * 16;
  const int tid = threadIdx.x;
  const int wave = tid >> 6, lane = tid & 63;
  const int cl = lane & 15, quad = lane >> 4;
  const int hcol = wave * 16 + cl;

  __shared__ __align__(16) ushort_t xbuf[2][2][16 * 256]; // [buf][gp] 32 KiB
  __shared__ __align__(16) ushort_t hbuf[2][16][136];     // 8.5 KiB

  // Whh^T fragments: n = g*128 + hcol, k = kt*32 + quad*8
  short8 Bf[4][4];
  const ushort_t* WTd = WhhT + (size_t)dir * (512 * 128);
#pragma unroll
  for (int g = 0; g < 4; g++)
#pragma unroll
    for (int kt = 0; kt < 4; kt++)
      Bf[g][kt] = *(const short8*)(WTd + (g * 128 + hcol) * 128 + kt * 32 + quad * 8);

  float cst[4] = {0.f, 0.f, 0.f, 0.f};
  float sum[4] = {0.f, 0.f, 0.f, 0.f};
  float mx[4]  = {-3.0e38f, -3.0e38f, -3.0e38f, -3.0e38f};
  float hLast[4] = {0.f, 0.f, 0.f, 0.f};
  ushort_t pend[4] = {0, 0, 0, 0};
  int tPrev = 0;

  for (int i = tid; i < 16 * 136; i += 512) ((ushort_t*)hbuf[0])[i] = 0;

  const ushort_t* xgp = xg + (size_t)blockIdx.y * 32768000ull;
  const int t0 = dir ? 49 : 0;
#pragma unroll
  for (int g2 = 0; g2 < 2; g2++)
    gload16(xgp + ((size_t)(g2 * 50 + t0) * 1280 + s0) * 256 + tid * 8,
            &xbuf[0][g2][0] + tid * 8);
  __syncthreads();   // drains the prologue copy

  for (int step = 0; step < 50; step++) {
    const int t = dir ? (49 - step) : step;
    const int cur = step & 1;

    if (step < 49) {                    // prefetch next step's x into other buf
      const int tn = dir ? (t - 1) : (t + 1);
#pragma unroll
      for (int g2 = 0; g2 < 2; g2++)
        gload16(xgp + ((size_t)(g2 * 50 + tn) * 1280 + s0) * 256 + tid * 8,
                &xbuf[cur ^ 1][g2][0] + tid * 8);
    }
    if (MODE == 0 && step > 0) {        // flush previous step's Y
#pragma unroll
      for (int r = 0; r < 4; r++)
        Y[((size_t)(s0 + quad * 4 + r) * 50 + tPrev) * 256 + dir * 128 + hcol] = pend[r];
    }

    short8 Af[4];
#pragma unroll
    for (int kt = 0; kt < 4; kt++)      // A: m=lane&15, k=quad*8+j
      Af[kt] = *(const short8*)(&hbuf[cur][cl][kt * 32 + quad * 8]);

    float4v acc[4];
#pragma unroll
    for (int g = 0; g < 4; g++) acc[g] = float4v{0.f, 0.f, 0.f, 0.f};
#pragma unroll
    for (int kt = 0; kt < 4; kt++)
#pragma unroll
      for (int g = 0; g < 4; g++)
        acc[g] = __builtin_amdgcn_mfma_f32_16x16x32_bf16(Af[kt], Bf[g][kt], acc[g], 0, 0, 0);

#pragma unroll
    for (int r = 0; r < 4; r++) {
      const int seq = quad * 4 + r;
      unsigned xif = *(const unsigned*)(&xbuf[cur][0][seq * 256 + hcol * 2]);
      unsigned xgo = *(const unsigned*)(&xbuf[cur][1][seq * 256 + hcol * 2]);
      float gi = acc[0][r] + bf2f((ushort_t)(xif & 0xffff));
      float gf = acc[1][r] + bf2f((ushort_t)(xif >> 16));
      float gg = acc[2][r] + bf2f((ushort_t)(xgo & 0xffff));
      float go = acc[3][r] + bf2f((ushort_t)(xgo >> 16));
      float ii = sigmoidf_(gi);
      float ff = sigmoidf_(gf);
      float gc = tanhf_(gg);
      float oo = sigmoidf_(go);
      float c = ff * cst[r] + ii * gc;
      cst[r] = c;
      float h = oo * tanhf_(c);
      ushort_t hb = f2bf(h);
      hbuf[cur ^ 1][seq][hcol] = hb;
      if (MODE == 0) {
        pend[r] = hb;
      } else {
        sum[r] += h;
        mx[r] = fmaxf(mx[r], h);
        hLast[r] = h;
      }
    }
    tPrev = t;
    __syncthreads();
  }

  if (MODE == 0) {
#pragma unroll
    for (int r = 0; r < 4; r++)
      Y[((size_t)(s0 + quad * 4 + r) * 50 + tPrev) * 256 + dir * 128 + hcol] = pend[r];
  } else {
#pragma unroll
    for (int r = 0; r < 4; r++) {
      const int seq = s0 + quad * 4 + r;
      const int c = dir * 128 + hcol;
      agg[(size_t)seq * 768 + c] = sum[r] * (1.0f / 50.0f);
      agg[(size_t)seq * 768 + 256 + c] = mx[r];
      agg[(size_t)seq * 768 + 512 + c] = hLast[r];   // h_n of this direction
    }
  }
}

// --------------------------- head: GEMM1 (fp32) -----------------------------
__global__ __launch_bounds__(256) void k_head1(
    const float* __restrict__ agg, const float* __restrict__ W1,
    const float* __restrict__ b1, float* __restrict__ h1)
{
  __shared__ float aggS[16][772];
  const int n0 = blockIdx.x * 16;
  const int c0 = blockIdx.y * 128;
  const int tid = threadIdx.x;
  for (int i = tid; i < 16 * 192; i += 256) {
    int row = i / 192, c4 = i % 192;
    *(float4v*)(&aggS[row][c4 * 4]) =
        *(const float4v*)(agg + (size_t)(n0 + row) * 768 + c4 * 4);
  }
  __syncthreads();
  const int cq = tid & 31;          // cols c0 + cq*4 .. +3
  const int rp = tid >> 5;          // rows rp*2, rp*2+1
  float acc0[4] = {0.f, 0.f, 0.f, 0.f}, acc1[4] = {0.f, 0.f, 0.f, 0.f};
#pragma unroll 4
  for (int k = 0; k < 768; k++) {
    float4v w = *(const float4v*)(W1 + (size_t)k * 512 + c0 + cq * 4);
    float a0 = aggS[rp * 2][k], a1 = aggS[rp * 2 + 1][k];
#pragma unroll
    for (int q = 0; q < 4; q++) { acc0[q] += a0 * w[q]; acc1[q] += a1 * w[q]; }
  }
#pragma unroll
  for (int q = 0; q < 4; q++) {
    int col = c0 + cq * 4 + q;
    float bb = b1[col];
    h1[(size_t)(n0 + rp * 2) * 512 + col] = acc0[q] + bb;
    h1[(size_t)(n0 + rp * 2 + 1) * 512 + col] = acc1[q] + bb;
  }
}

// --------------------------- head: LN + relu + GEMM2 (fp32) -----------------
__global__ __launch_bounds__(256) void k_head2(
    const float* __restrict__ h1, const float* __restrict__ ln_g,
    const float* __restrict__ ln_b, const float* __restrict__ W2,
    const float* __restrict__ b2, float* __restrict__ out)
{
  __shared__ float hnS[8][516];
  const int n0 = blockIdx.x * 8;
  const int tid = threadIdx.x;
  const int row = tid >> 5, li = tid & 31;
  const float* hr = h1 + (size_t)(n0 + row) * 512;
  float sum = 0.f, sq = 0.f;
  float v[16];
#pragma unroll
  for (int j = 0; j < 16; j++) {
    v[j] = hr[li + 32 * j];
    sum += v[j]; sq += v[j] * v[j];
  }
#pragma unroll
  for (int m = 1; m <= 16; m <<= 1) {
    sum += __shfl_xor(sum, m);
    sq  += __shfl_xor(sq, m);
  }
  float mu = sum * (1.0f / 512.0f);
  float var = sq * (1.0f / 512.0f) - mu * mu;
  float rs = rsqrtf(var + 1e-5f);
#pragma unroll
  for (int j = 0; j < 16; j++) {
    int col = li + 32 * j;
    float y = (v[j] - mu) * rs * ln_g[col] + ln_b[col];
    hnS[row][col] = fmaxf(y, 0.0f);
  }
  __syncthreads();
  const int cq = tid & 63, rp = tid >> 6;   // cols cq*4..+3; rows rp*2, rp*2+1
  float acc0[4] = {0.f, 0.f, 0.f, 0.f}, acc1[4] = {0.f, 0.f, 0.f, 0.f};
#pragma unroll 4
  for (int k = 0; k < 512; k++) {
    float4v w = *(const float4v*)(W2 + (size_t)k * 256 + cq * 4);
    float a0 = hnS[rp * 2][k], a1 = hnS[rp * 2 + 1][k];
#pragma unroll
    for (int q = 0; q < 4; q++) { acc0[q] += a0 * w[q]; acc1[q] += a1 * w[q]; }
  }
#pragma unroll
  for (int q = 0; q < 4; q++) {
    int col = cq * 4 + q;
    float bb = b2[col];
    out[(size_t)(n0 + rp * 2) * 256 + col] = acc0[q] + bb;
    out[(size_t)(n0 + rp * 2 + 1) * 256 + col] = acc1[q] + bb;
  }
}

// --------------------------- launcher --------------------------------------
extern "C" void kernel_launch(void* const* d_in, const int* in_sizes, int n_in,
                              void* d_out, int out_size, void* d_ws, size_t ws_size,
                              hipStream_t stream)
{
  (void)in_sizes; (void)n_in; (void)out_size;
  const float* imu   = (const float*)d_in[0];
  const float* W_in  = (const float*)d_in[1];
  const float* b_in  = (const float*)d_in[2];
  const float* Wih0  = (const float*)d_in[3];
  const float* Whh0  = (const float*)d_in[4];
  const float* bih0  = (const float*)d_in[5];
  const float* bhh0  = (const float*)d_in[6];
  const float* Wih1  = (const float*)d_in[7];
  const float* Whh1  = (const float*)d_in[8];
  const float* bih1  = (const float*)d_in[9];
  const float* bhh1  = (const float*)d_in[10];
  const float* Wih2  = (const float*)d_in[11];
  const float* Whh2  = (const float*)d_in[12];
  const float* bih2  = (const float*)d_in[13];
  const float* bhh2  = (const float*)d_in[14];
  const float* Wout1 = (const float*)d_in[15];
  const float* bout1 = (const float*)d_in[16];
  const float* ln_g  = (const float*)d_in[17];
  const float* ln_b  = (const float*)d_in[18];
  const float* Wout2 = (const float*)d_in[19];
  const float* bout2 = (const float*)d_in[20];
  float* out = (float*)d_out;
  char* ws = (char*)d_ws;

  // ws layout (bytes)
  const size_t ACT0_OFF = 0;                      // 8,192,000  (64000*64*2)
  const size_t YA_OFF   = 8192000;                // 32,768,000 (64000*256*2)
  const size_t YB_OFF   = 40960000;               // 32,768,000
  const size_t XG_OFF   = 73728000;               // 131,072,000 (both) / 65,536,000 (serial)
  const size_t XG_BOTH  = 131072000, XG_SER = 65536000;
  const size_t WT_SZ    = 1966080;                // 983,040 bf16 elems
  const bool both = ws_size >= XG_OFF + XG_BOTH + WT_SZ;
  const size_t WT_OFF = XG_OFF + (both ? XG_BOTH : XG_SER);

  ushort_t* act0 = (ushort_t*)(ws + ACT0_OFF);
  ushort_t* Ya   = (ushort_t*)(ws + YA_OFF);
  ushort_t* Yb   = (ushort_t*)(ws + YB_OFF);
  ushort_t* xg   = (ushort_t*)(ws + XG_OFF);
  ushort_t* WT   = (ushort_t*)(ws + WT_OFF);
  float* agg = (float*)(ws + 0);                  // reuses act0 region (dead by then)
  float* h1  = (float*)(ws + 4194304);

  ushort_t* WT_ih0 = WT + 0;
  ushort_t* WT_ih1 = WT + 65536;
  ushort_t* WT_ih2 = WT + 327680;
  ushort_t* WT_hh0 = WT + 589824;
  ushort_t* WT_hh1 = WT + 720896;
  ushort_t* WT_hh2 = WT + 851968;

  k_prep<<<480, 256, 0, stream>>>(Wih0, Wih1, Wih2, Whh0, Whh1, Whh2, WT);
  k_inproj<<<16000, 256, 0, stream>>>(imu, W_in, b_in, act0);

  const int nPass = both ? 1 : 2;
  const int gz = both ? 2 : 1;

  const ushort_t* Xs[3]   = {act0, Ya, Yb};
  ushort_t* Ys[3]         = {Ya, Yb, Ya};
  const ushort_t* WTih[3] = {WT_ih0, WT_ih1, WT_ih2};
  const ushort_t* WThh[3] = {WT_hh0, WT_hh1, WT_hh2};
  const float* bihs[3]    = {bih0, bih1, bih2};
  const float* bhhs[3]    = {bhh0, bhh1, bhh2};

  for (int layer = 0; layer < 3; layer++) {
    for (int p = 0; p < nPass; p++) {
      int dirBase = both ? 0 : p;
      if (layer == 0)
        k_xg_gemm<64><<<dim3(1000, 2, gz), 256, 0, stream>>>(
            Xs[0], WTih[0], bihs[0], bhhs[0], xg, dirBase);
      else
        k_xg_gemm<256><<<dim3(1000, 2, gz), 256, 0, stream>>>(
            Xs[layer], WTih[layer], bihs[layer], bhhs[layer], xg, dirBase);
      if (layer < 2)
        k_scan<0><<<dim3(80, gz), 512, 0, stream>>>(xg, WThh[layer], Ys[layer], agg, dirBase);
      else
        k_scan<1><<<dim3(80, gz), 512, 0, stream>>>(xg, WThh[layer], Ys[layer], agg, dirBase);
    }
  }

  k_head1<<<dim3(80, 4), 256, 0, stream>>>(agg, Wout1, bout1, h1);
  k_head2<<<160, 256, 0, stream>>>(h1, ln_g, ln_b, Wout2, bout2, out);
}

// Round 4
// 497.722 us; speedup vs baseline: 1.5023x; 1.1768x over previous
//
#include <hip/hip_runtime.h>
#include <stdint.h>

// ---------------------------------------------------------------------------
// TimeAwareIMULSTMEncoder on MI355X (gfx950) — round 4
// vs round 3:
//  * k_head1/k_head2 (fp32 latency-bound loops, 93+~50 us, MfmaUtil 0,
//    VALUBusy 8%) replaced by ONE fused MFMA kernel k_head:
//    GEMM1(bf16, K=768) -> bias -> LayerNorm (quad-shuffle + LDS reduce)
//    -> relu -> bf16 A-layout in LDS -> GEMM2(bf16, K=512) -> fp32 out.
//  * scan MODE 1 writes agg in bf16 (head consumes bf16 A directly).
//  * k_prep also transposes Wout1 [768][512] -> [512][768] bf16 and
//    Wout2 [512][256] -> [256][512] bf16 (n-major B operands).
// ---------------------------------------------------------------------------

typedef unsigned short ushort_t;
typedef short short8 __attribute__((ext_vector_type(8)));     // 8 bf16 (4 VGPRs)
typedef float float4v __attribute__((ext_vector_type(4)));    // MFMA acc

#define DEV_INLINE __device__ __forceinline__

DEV_INLINE ushort_t f2bf(float f) {                 // RNE f32 -> bf16 bits
  union { float f; unsigned u; } v; v.f = f;
  unsigned r = v.u + 0x7fffu + ((v.u >> 16) & 1u);
  return (ushort_t)(r >> 16);
}
DEV_INLINE float bf2f(ushort_t s) {
  union { unsigned u; float f; } v; v.u = ((unsigned)s) << 16;
  return v.f;
}
DEV_INLINE float sigmoidf_(float x) {
  return __builtin_amdgcn_rcpf(1.0f + __expf(-x));
}
DEV_INLINE float tanhf_(float x) {                  // 1 - 2/(1+e^{2x}); safe at +-inf
  return 1.0f - 2.0f * __builtin_amdgcn_rcpf(1.0f + __expf(2.0f * x));
}

// async global->LDS, 16B per lane; dst must be wave-uniform base + lane*16.
DEV_INLINE void gload16(const ushort_t* g, ushort_t* l) {
  __builtin_amdgcn_global_load_lds(
      (const __attribute__((address_space(1))) unsigned int*)g,
      (__attribute__((address_space(3))) unsigned int*)l, 16, 0, 0);
}

// --------------------------- weight prep (tiled transpose) ------------------
// Generic [R][C] f32 -> [C][R] bf16 transpose in 32(k) x 64(n) LDS tiles.
// WT arena (elements):
//   Wih0 @0 [2*512*64] | Wih1 @65536 [2*512*256] | Wih2 @327680 [2*512*256]
//   Whh0 @589824 | Whh1 @720896 | Whh2 @851968 (each [2*512*128])
//   W1T  @983040 [512*768] | W2T @1376256 [256*512]   (total 1507328 elems)
__global__ __launch_bounds__(256) void k_prep(
    const float* __restrict__ Wih0, const float* __restrict__ Wih1,
    const float* __restrict__ Wih2, const float* __restrict__ Whh0,
    const float* __restrict__ Whh1, const float* __restrict__ Whh2,
    const float* __restrict__ Wout1, const float* __restrict__ Wout2,
    ushort_t* __restrict__ WT)
{
  __shared__ float T[32][65];
  const int b = blockIdx.x;
  const int tid = threadIdx.x;
  const float* S; int Kd, C; size_t dstBase; int kt, nt;
  if (b < 32) {
    int rel = b; int d = (rel >> 3) / 2; kt = (rel >> 3) & 1; nt = rel & 7;
    S = Wih0 + (size_t)d * 64 * 512; C = 512; Kd = 64;
    dstBase = 0 + (size_t)d * 512 * 64;
  } else if (b < 160) {
    int rel = b - 32; int d = (rel >> 3) / 8; kt = (rel >> 3) & 7; nt = rel & 7;
    S = Wih1 + (size_t)d * 256 * 512; C = 512; Kd = 256;
    dstBase = 65536 + (size_t)d * 512 * 256;
  } else if (b < 288) {
    int rel = b - 160; int d = (rel >> 3) / 8; kt = (rel >> 3) & 7; nt = rel & 7;
    S = Wih2 + (size_t)d * 256 * 512; C = 512; Kd = 256;
    dstBase = 327680 + (size_t)d * 512 * 256;
  } else if (b < 352) {
    int rel = b - 288; int d = (rel >> 3) / 4; kt = (rel >> 3) & 3; nt = rel & 7;
    S = Whh0 + (size_t)d * 128 * 512; C = 512; Kd = 128;
    dstBase = 589824 + (size_t)d * 512 * 128;
  } else if (b < 416) {
    int rel = b - 352; int d = (rel >> 3) / 4; kt = (rel >> 3) & 3; nt = rel & 7;
    S = Whh1 + (size_t)d * 128 * 512; C = 512; Kd = 128;
    dstBase = 720896 + (size_t)d * 512 * 128;
  } else if (b < 480) {
    int rel = b - 416; int d = (rel >> 3) / 4; kt = (rel >> 3) & 3; nt = rel & 7;
    S = Whh2 + (size_t)d * 128 * 512; C = 512; Kd = 128;
    dstBase = 851968 + (size_t)d * 512 * 128;
  } else if (b < 672) {
    int rel = b - 480; kt = rel >> 3; nt = rel & 7;
    S = Wout1; C = 512; Kd = 768; dstBase = 983040;
  } else {
    int rel = b - 672; kt = rel >> 2; nt = rel & 3;
    S = Wout2; C = 256; Kd = 512; dstBase = 1376256;
  }
  const int k0 = kt * 32, n0 = nt * 64;
  {
    int kr = tid >> 6;                // 0..3
    int n  = tid & 63;
#pragma unroll
    for (int i = 0; i < 8; i++)
      T[i * 4 + kr][n] = S[(size_t)(k0 + i * 4 + kr) * C + n0 + n];
  }
  __syncthreads();
  {
    int n = tid >> 2;                 // 0..63
    int ko = (tid & 3) * 8;           // 0,8,16,24
    ushort_t pk[8];
#pragma unroll
    for (int j = 0; j < 8; j++) pk[j] = f2bf(T[ko + j][n]);
    *(uint4*)(WT + dstBase + (size_t)(n0 + n) * Kd + k0 + ko) = *(uint4*)pk;
  }
}

// --------------------------- input projection ------------------------------
__global__ __launch_bounds__(256) void k_inproj(
    const float* __restrict__ imu, const float* __restrict__ W_in,
    const float* __restrict__ b_in, ushort_t* __restrict__ act0)
{
  int idx = blockIdx.x * 256 + threadIdx.x;   // 64000*64 exactly
  int j = idx & 63, r = idx >> 6;
  int l = r % 50;
  const float* x = imu + (size_t)r * 6;
  float acc = b_in[j];
#pragma unroll
  for (int d = 0; d < 6; d++) acc += x[d] * W_in[d * 64 + j];
  acc += (l * (1.0f / 49.0f)) * W_in[6 * 64 + j] + W_in[7 * 64 + j]; // t, rate=1
  act0[idx] = f2bf(fmaxf(acc, 0.0f));
}

// --------------------------- xg GEMM (bf16 MFMA, 64x256 tile) ---------------
template <int K>
__global__ __launch_bounds__(256, 3) void k_xg_gemm(
    const ushort_t* __restrict__ X,    // [64000][K] bf16 (m-major)
    const ushort_t* __restrict__ WT,   // [2][512][K] bf16 (n-major)
    const float* __restrict__ bih, const float* __restrict__ bhh, // [2][512]
    ushort_t* __restrict__ xg,         // [dirSlot][2][50][1280][256]
    int dirBase)
{
  __shared__ __align__(16) ushort_t As[2][64 * 32];    //  8 KiB
  __shared__ __align__(16) ushort_t Bs[2][256 * 32];   // 32 KiB
  const int dir = blockIdx.z + dirBase;
  const int gp  = blockIdx.y;
  const int m0  = blockIdx.x * 64;
  const int tid = threadIdx.x;
  const int wave = tid >> 6, lane = tid & 63;
  const int cl = lane & 15, quad = lane >> 4;
  const ushort_t* Wd = WT + ((size_t)dir * 512 + gp * 256) * K;   // 256 rows

  float4v acc[4][2][2];
#pragma unroll
  for (int i = 0; i < 4; i++)
#pragma unroll
    for (int u = 0; u < 2; u++)
#pragma unroll
      for (int q = 0; q < 2; q++) acc[i][u][q] = float4v{0.f, 0.f, 0.f, 0.f};

  const int srow = lane >> 2;         // 0..15
  const int scol = (lane & 3) * 8;    // 0,8,16,24

#define STAGE(buf, kb)                                                        \
  {                                                                           \
    gload16(X + (size_t)(m0 + wave * 16 + srow) * K + (kb) + scol,            \
            &As[buf][wave * 16 * 32] + lane * 8);                             \
    _Pragma("unroll")                                                         \
    for (int j = 0; j < 4; j++)                                               \
      gload16(Wd + (size_t)(wave * 64 + j * 16 + srow) * K + (kb) + scol,     \
              &Bs[buf][(wave * 64 + j * 16) * 32] + lane * 8);                \
  }

  STAGE(0, 0)
  for (int kb = 0; kb < K; kb += 32) {
    const int cur = (kb >> 5) & 1;
    __syncthreads();                  // drains DMA for cur; protects cur^1 reuse
    if (kb + 32 < K) STAGE(cur ^ 1, kb + 32)
    short8 Af[4], Bf[2][2];
#pragma unroll
    for (int i = 0; i < 4; i++)
      Af[i] = *(const short8*)(&As[cur][(i * 16 + cl) * 32 + quad * 8]);
#pragma unroll
    for (int u = 0; u < 2; u++)
#pragma unroll
      for (int q = 0; q < 2; q++)
        Bf[u][q] = *(const short8*)(&Bs[cur][(q * 128 + wave * 32 + u * 16 + cl) * 32 + quad * 8]);
#pragma unroll
    for (int i = 0; i < 4; i++)
#pragma unroll
      for (int u = 0; u < 2; u++)
#pragma unroll
        for (int q = 0; q < 2; q++)
          acc[i][u][q] = __builtin_amdgcn_mfma_f32_16x16x32_bf16(Af[i], Bf[u][q], acc[i][u][q], 0, 0, 0);
  }
#undef STAGE

  ushort_t* outp = xg + (size_t)blockIdx.z * 32768000ull + (size_t)gp * 16384000ull;
  const int gbase = dir * 512 + gp * 256;
#pragma unroll
  for (int u = 0; u < 2; u++) {
    const int hc = wave * 32 + u * 16 + cl;
    float b0 = bih[gbase + hc] + bhh[gbase + hc];
    float b1 = bih[gbase + 128 + hc] + bhh[gbase + 128 + hc];
#pragma unroll
    for (int i = 0; i < 4; i++) {
#pragma unroll
      for (int r = 0; r < 4; r++) {
        int m = m0 + i * 16 + quad * 4 + r;   // D: row=quad*4+r, col=lane&15
        int seq = m / 50, t = m - seq * 50;
        unsigned pk = (unsigned)f2bf(acc[i][u][0][r] + b0) |
                      ((unsigned)f2bf(acc[i][u][1][r] + b1) << 16);
        *(unsigned*)(outp + ((size_t)t * 1280 + seq) * 256 + hc * 2) = pk;
      }
    }
  }
}

// --------------------------- LSTM scan -------------------------------------
// MODE 0: write Y. MODE 1: fused aggregation, agg emitted in bf16.
template <int MODE>
__global__ __launch_bounds__(512, 1) void k_scan(
    const ushort_t* __restrict__ xg,    // [dirSlot][2][50][1280][256]
    const ushort_t* __restrict__ WhhT,  // [2][512][128] bf16 n-major
    ushort_t* __restrict__ Y,           // [64000][256] bf16
    ushort_t* __restrict__ aggb,        // [1280][768] bf16
    int dirBase)
{
  const int dir = blockIdx.y + dirBase;
  const int s0 = blockIdx.x * 16;
  const int tid = threadIdx.x;
  const int wave = tid >> 6, lane = tid & 63;
  const int cl = lane & 15, quad = lane >> 4;
  const int hcol = wave * 16 + cl;

  __shared__ __align__(16) ushort_t xbuf[2][2][16 * 256]; // [buf][gp] 32 KiB
  __shared__ __align__(16) ushort_t hbuf[2][16][136];     // 8.5 KiB

  short8 Bf[4][4];
  const ushort_t* WTd = WhhT + (size_t)dir * (512 * 128);
#pragma unroll
  for (int g = 0; g < 4; g++)
#pragma unroll
    for (int kt = 0; kt < 4; kt++)
      Bf[g][kt] = *(const short8*)(WTd + (g * 128 + hcol) * 128 + kt * 32 + quad * 8);

  float cst[4] = {0.f, 0.f, 0.f, 0.f};
  float sum[4] = {0.f, 0.f, 0.f, 0.f};
  float mx[4]  = {-3.0e38f, -3.0e38f, -3.0e38f, -3.0e38f};
  float hLast[4] = {0.f, 0.f, 0.f, 0.f};
  ushort_t pend[4] = {0, 0, 0, 0};
  int tPrev = 0;

  for (int i = tid; i < 16 * 136; i += 512) ((ushort_t*)hbuf[0])[i] = 0;

  const ushort_t* xgp = xg + (size_t)blockIdx.y * 32768000ull;
  const int t0 = dir ? 49 : 0;
#pragma unroll
  for (int g2 = 0; g2 < 2; g2++)
    gload16(xgp + ((size_t)(g2 * 50 + t0) * 1280 + s0) * 256 + tid * 8,
            &xbuf[0][g2][0] + tid * 8);
  __syncthreads();   // drains the prologue copy

  for (int step = 0; step < 50; step++) {
    const int t = dir ? (49 - step) : step;
    const int cur = step & 1;

    if (step < 49) {                    // prefetch next step's x into other buf
      const int tn = dir ? (t - 1) : (t + 1);
#pragma unroll
      for (int g2 = 0; g2 < 2; g2++)
        gload16(xgp + ((size_t)(g2 * 50 + tn) * 1280 + s0) * 256 + tid * 8,
                &xbuf[cur ^ 1][g2][0] + tid * 8);
    }
    if (MODE == 0 && step > 0) {        // flush previous step's Y
#pragma unroll
      for (int r = 0; r < 4; r++)
        Y[((size_t)(s0 + quad * 4 + r) * 50 + tPrev) * 256 + dir * 128 + hcol] = pend[r];
    }

    short8 Af[4];
#pragma unroll
    for (int kt = 0; kt < 4; kt++)      // A: m=lane&15, k=quad*8+j
      Af[kt] = *(const short8*)(&hbuf[cur][cl][kt * 32 + quad * 8]);

    float4v acc[4];
#pragma unroll
    for (int g = 0; g < 4; g++) acc[g] = float4v{0.f, 0.f, 0.f, 0.f};
#pragma unroll
    for (int kt = 0; kt < 4; kt++)
#pragma unroll
      for (int g = 0; g < 4; g++)
        acc[g] = __builtin_amdgcn_mfma_f32_16x16x32_bf16(Af[kt], Bf[g][kt], acc[g], 0, 0, 0);

#pragma unroll
    for (int r = 0; r < 4; r++) {
      const int seq = quad * 4 + r;
      unsigned xif = *(const unsigned*)(&xbuf[cur][0][seq * 256 + hcol * 2]);
      unsigned xgo = *(const unsigned*)(&xbuf[cur][1][seq * 256 + hcol * 2]);
      float gi = acc[0][r] + bf2f((ushort_t)(xif & 0xffff));
      float gf = acc[1][r] + bf2f((ushort_t)(xif >> 16));
      float gg = acc[2][r] + bf2f((ushort_t)(xgo & 0xffff));
      float go = acc[3][r] + bf2f((ushort_t)(xgo >> 16));
      float ii = sigmoidf_(gi);
      float ff = sigmoidf_(gf);
      float gc = tanhf_(gg);
      float oo = sigmoidf_(go);
      float c = ff * cst[r] + ii * gc;
      cst[r] = c;
      float h = oo * tanhf_(c);
      ushort_t hb = f2bf(h);
      hbuf[cur ^ 1][seq][hcol] = hb;
      if (MODE == 0) {
        pend[r] = hb;
      } else {
        sum[r] += h;
        mx[r] = fmaxf(mx[r], h);
        hLast[r] = h;
      }
    }
    tPrev = t;
    __syncthreads();
  }

  if (MODE == 0) {
#pragma unroll
    for (int r = 0; r < 4; r++)
      Y[((size_t)(s0 + quad * 4 + r) * 50 + tPrev) * 256 + dir * 128 + hcol] = pend[r];
  } else {
#pragma unroll
    for (int r = 0; r < 4; r++) {
      const int seq = s0 + quad * 4 + r;
      const int c = dir * 128 + hcol;
      aggb[(size_t)seq * 768 + c]       = f2bf(sum[r] * (1.0f / 50.0f));
      aggb[(size_t)seq * 768 + 256 + c] = f2bf(mx[r]);
      aggb[(size_t)seq * 768 + 512 + c] = f2bf(hLast[r]);   // h_n of this dir
    }
  }
}

// --------------------------- fused head -------------------------------------
// 20 blocks x 512 thr. Per block: 64 rows.
//   GEMM1: agg[64x768]bf16 @ W1T -> 64x512 (acc fp32), + bout1
//   LayerNorm over 512 (quad-shuffle 16-lane reduce -> LDS cross-wave) + relu
//   -> bf16 into LDS A-layout -> GEMM2: [64x512] @ W2T -> 64x256 + bout2 (f32)
__global__ __launch_bounds__(512, 1) void k_head(
    const ushort_t* __restrict__ aggb,  // [1280][768] bf16
    const ushort_t* __restrict__ W1T,   // [512][768] bf16
    const float* __restrict__ b1, const float* __restrict__ ln_g,
    const float* __restrict__ ln_b,
    const ushort_t* __restrict__ W2T,   // [256][512] bf16
    const float* __restrict__ b2, float* __restrict__ out) // [1280][256]
{
  __shared__ __align__(16) char smem[78336];
  ushort_t* AsB = (ushort_t*)smem;            // [2][64*32]   (8 KiB)
  ushort_t* BsB = (ushort_t*)(smem + 8192);   // [2][512*32]  (64 KiB)
  ushort_t* hn  = (ushort_t*)smem;            // [64][520] aliased (66.6 KiB)
  float* partS  = (float*)(smem + 73728);     // [64][8]
  float* partQ  = partS + 512;                // [64][8]
  float* muS    = partQ + 512;                // [64]
  float* rsS    = muS + 64;                   // [64]

  const int m0 = blockIdx.x * 64;
  const int tid = threadIdx.x;
  const int wave = tid >> 6, lane = tid & 63;
  const int cl = lane & 15, quad = lane >> 4;
  const int srow = lane >> 2, scol = (lane & 3) * 8;

  float4v acc1[4][4];
#pragma unroll
  for (int i = 0; i < 4; i++)
#pragma unroll
    for (int v = 0; v < 4; v++) acc1[i][v] = float4v{0.f, 0.f, 0.f, 0.f};

#define STAGE1(buf, kb)                                                       \
  {                                                                           \
    if (wave < 4)                                                             \
      gload16(aggb + (size_t)(m0 + wave * 16 + srow) * 768 + (kb) + scol,     \
              AsB + (buf) * 2048 + wave * 16 * 32 + lane * 8);                \
    _Pragma("unroll")                                                         \
    for (int j = 0; j < 4; j++)                                               \
      gload16(W1T + (size_t)(wave * 64 + j * 16 + srow) * 768 + (kb) + scol,  \
              BsB + (buf) * 16384 + (wave * 64 + j * 16) * 32 + lane * 8);    \
  }

  STAGE1(0, 0)
  for (int kb = 0; kb < 768; kb += 32) {
    const int cur = (kb >> 5) & 1;
    __syncthreads();
    if (kb + 32 < 768) STAGE1(cur ^ 1, kb + 32)
    short8 Af[4], Bf[4];
#pragma unroll
    for (int i = 0; i < 4; i++)
      Af[i] = *(const short8*)(AsB + cur * 2048 + (i * 16 + cl) * 32 + quad * 8);
#pragma unroll
    for (int v = 0; v < 4; v++)
      Bf[v] = *(const short8*)(BsB + cur * 16384 + (wave * 64 + v * 16 + cl) * 32 + quad * 8);
#pragma unroll
    for (int i = 0; i < 4; i++)
#pragma unroll
      for (int v = 0; v < 4; v++)
        acc1[i][v] = __builtin_amdgcn_mfma_f32_16x16x32_bf16(Af[i], Bf[v], acc1[i][v], 0, 0, 0);
  }
#undef STAGE1
  __syncthreads();          // all waves done with AsB/BsB (hn aliases them)

  float bcol[4], lg[4], lb[4];
#pragma unroll
  for (int v = 0; v < 4; v++) {
    int col = wave * 64 + v * 16 + cl;
    bcol[v] = b1[col]; lg[v] = ln_g[col]; lb[v] = ln_b[col];
  }

  // per-row partial sums over this wave's 64 cols (rows live in one quad)
#pragma unroll
  for (int i = 0; i < 4; i++) {
#pragma unroll
    for (int r = 0; r < 4; r++) {
      float s = 0.f, q = 0.f;
#pragma unroll
      for (int v = 0; v < 4; v++) {
        float x = acc1[i][v][r] + bcol[v];
        s += x; q += x * x;
      }
#pragma unroll
      for (int m = 1; m <= 8; m <<= 1) {
        s += __shfl_xor(s, m);
        q += __shfl_xor(q, m);
      }
      if (cl == 0) {
        int row = i * 16 + quad * 4 + r;
        partS[row * 8 + wave] = s;
        partQ[row * 8 + wave] = q;
      }
    }
  }
  __syncthreads();
  if (tid < 64) {
    float s = 0.f, q = 0.f;
#pragma unroll
    for (int w = 0; w < 8; w++) { s += partS[tid * 8 + w]; q += partQ[tid * 8 + w]; }
    float mu = s * (1.0f / 512.0f);
    float var = q * (1.0f / 512.0f) - mu * mu;
    muS[tid] = mu;
    rsS[tid] = rsqrtf(var + 1e-5f);
  }
  __syncthreads();

  // normalize + relu -> hn (bf16, [64][520], A-layout-readable)
#pragma unroll
  for (int i = 0; i < 4; i++) {
#pragma unroll
    for (int r = 0; r < 4; r++) {
      int row = i * 16 + quad * 4 + r;
      float mu = muS[row], rs = rsS[row];
#pragma unroll
      for (int v = 0; v < 4; v++) {
        int col = wave * 64 + v * 16 + cl;
        float x = acc1[i][v][r] + bcol[v];
        float y = (x - mu) * rs * lg[v] + lb[v];
        hn[row * 520 + col] = f2bf(fmaxf(y, 0.0f));
      }
    }
  }
  __syncthreads();

  // GEMM2: K=512; B-frags direct from L2 (W2T read by all 20 blocks)
  float4v acc2[4][2];
#pragma unroll
  for (int i = 0; i < 4; i++)
#pragma unroll
    for (int u = 0; u < 2; u++) acc2[i][u] = float4v{0.f, 0.f, 0.f, 0.f};
  for (int kt = 0; kt < 16; kt++) {
    short8 Af2[4], Bf2[2];
#pragma unroll
    for (int u = 0; u < 2; u++)
      Bf2[u] = *(const short8*)(W2T + (size_t)(wave * 32 + u * 16 + cl) * 512 + kt * 32 + quad * 8);
#pragma unroll
    for (int i = 0; i < 4; i++)
      Af2[i] = *(const short8*)(hn + (i * 16 + cl) * 520 + kt * 32 + quad * 8);
#pragma unroll
    for (int i = 0; i < 4; i++)
#pragma unroll
      for (int u = 0; u < 2; u++)
        acc2[i][u] = __builtin_amdgcn_mfma_f32_16x16x32_bf16(Af2[i], Bf2[u], acc2[i][u], 0, 0, 0);
  }
#pragma unroll
  for (int u = 0; u < 2; u++) {
    int col = wave * 32 + u * 16 + cl;
    float bb = b2[col];
#pragma unroll
    for (int i = 0; i < 4; i++)
#pragma unroll
      for (int r = 0; r < 4; r++)
        out[(size_t)(m0 + i * 16 + quad * 4 + r) * 256 + col] = acc2[i][u][r] + bb;
  }
}

// --------------------------- launcher --------------------------------------
extern "C" void kernel_launch(void* const* d_in, const int* in_sizes, int n_in,
                              void* d_out, int out_size, void* d_ws, size_t ws_size,
                              hipStream_t stream)
{
  (void)in_sizes; (void)n_in; (void)out_size;
  const float* imu   = (const float*)d_in[0];
  const float* W_in  = (const float*)d_in[1];
  const float* b_in  = (const float*)d_in[2];
  const float* Wih0  = (const float*)d_in[3];
  const float* Whh0  = (const float*)d_in[4];
  const float* bih0  = (const float*)d_in[5];
  const float* bhh0  = (const float*)d_in[6];
  const float* Wih1  = (const float*)d_in[7];
  const float* Whh1  = (const float*)d_in[8];
  const float* bih1  = (const float*)d_in[9];
  const float* bhh1  = (const float*)d_in[10];
  const float* Wih2  = (const float*)d_in[11];
  const float* Whh2  = (const float*)d_in[12];
  const float* bih2  = (const float*)d_in[13];
  const float* bhh2  = (const float*)d_in[14];
  const float* Wout1 = (const float*)d_in[15];
  const float* bout1 = (const float*)d_in[16];
  const float* ln_g  = (const float*)d_in[17];
  const float* ln_b  = (const float*)d_in[18];
  const float* Wout2 = (const float*)d_in[19];
  const float* bout2 = (const float*)d_in[20];
  float* out = (float*)d_out;
  char* ws = (char*)d_ws;

  // ws layout (bytes)
  const size_t ACT0_OFF = 0;                      // 8,192,000  (64000*64*2)
  const size_t YA_OFF   = 8192000;                // 32,768,000 (64000*256*2)
  const size_t YB_OFF   = 40960000;               // 32,768,000
  const size_t XG_OFF   = 73728000;               // 131,072,000 (both) / 65,536,000 (serial)
  const size_t XG_BOTH  = 131072000, XG_SER = 65536000;
  const size_t WT_SZ    = 3014656;                // 1,507,328 bf16 elems
  const bool both = ws_size >= XG_OFF + XG_BOTH + WT_SZ;
  const size_t WT_OFF = XG_OFF + (both ? XG_BOTH : XG_SER);

  ushort_t* act0 = (ushort_t*)(ws + ACT0_OFF);
  ushort_t* Ya   = (ushort_t*)(ws + YA_OFF);
  ushort_t* Yb   = (ushort_t*)(ws + YB_OFF);
  ushort_t* xg   = (ushort_t*)(ws + XG_OFF);
  ushort_t* WT   = (ushort_t*)(ws + WT_OFF);
  ushort_t* aggb = (ushort_t*)(ws + 0);           // reuses act0 region (dead by then)

  ushort_t* WT_ih0 = WT + 0;
  ushort_t* WT_ih1 = WT + 65536;
  ushort_t* WT_ih2 = WT + 327680;
  ushort_t* WT_hh0 = WT + 589824;
  ushort_t* WT_hh1 = WT + 720896;
  ushort_t* WT_hh2 = WT + 851968;
  ushort_t* W1T    = WT + 983040;
  ushort_t* W2T    = WT + 1376256;

  k_prep<<<736, 256, 0, stream>>>(Wih0, Wih1, Wih2, Whh0, Whh1, Whh2,
                                  Wout1, Wout2, WT);
  k_inproj<<<16000, 256, 0, stream>>>(imu, W_in, b_in, act0);

  const int nPass = both ? 1 : 2;
  const int gz = both ? 2 : 1;

  const ushort_t* Xs[3]   = {act0, Ya, Yb};
  ushort_t* Ys[3]         = {Ya, Yb, Ya};
  const ushort_t* WTih[3] = {WT_ih0, WT_ih1, WT_ih2};
  const ushort_t* WThh[3] = {WT_hh0, WT_hh1, WT_hh2};
  const float* bihs[3]    = {bih0, bih1, bih2};
  const float* bhhs[3]    = {bhh0, bhh1, bhh2};

  for (int layer = 0; layer < 3; layer++) {
    for (int p = 0; p < nPass; p++) {
      int dirBase = both ? 0 : p;
      if (layer == 0)
        k_xg_gemm<64><<<dim3(1000, 2, gz), 256, 0, stream>>>(
            Xs[0], WTih[0], bihs[0], bhhs[0], xg, dirBase);
      else
        k_xg_gemm<256><<<dim3(1000, 2, gz), 256, 0, stream>>>(
            Xs[layer], WTih[layer], bihs[layer], bhhs[layer], xg, dirBase);
      if (layer < 2)
        k_scan<0><<<dim3(80, gz), 512, 0, stream>>>(xg, WThh[layer], Ys[layer], aggb, dirBase);
      else
        k_scan<1><<<dim3(80, gz), 512, 0, stream>>>(xg, WThh[layer], Ys[layer], aggb, dirBase);
    }
  }

  k_head<<<20, 512, 0, stream>>>(aggb, W1T, bout1, ln_g, ln_b, W2T, bout2, out);
}

// Round 5
// 492.640 us; speedup vs baseline: 1.5178x; 1.0103x over previous
//
#include <hip/hip_runtime.h>
#include <stdint.h>

// ---------------------------------------------------------------------------
// TimeAwareIMULSTMEncoder on MI355X (gfx950) — round 5
// vs round 4 (only k_scan restructured):
//  * k_scan: 1024 thr / 16 waves. Gate-split MFMA (wave (gp,hg): 2 gates x
//    16 hcols -> 8 MFMAs/wave, 4 waves/SIMD). Pre-activation gate sums
//    exchanged through LDS (P0/P1, float2, 2-way-free b64) so pointwise is
//    2 cells/lane (was 4) -> per-lane transcendentals halve.
//  * x gates loaded straight into VGPRs one step ahead (4 coalesced b32) —
//    no global_load_lds in the scan loop -> no vmcnt(0) barrier drain.
// ---------------------------------------------------------------------------

typedef unsigned short ushort_t;
typedef short short8 __attribute__((ext_vector_type(8)));     // 8 bf16 (4 VGPRs)
typedef float float4v __attribute__((ext_vector_type(4)));    // MFMA acc

#define DEV_INLINE __device__ __forceinline__

DEV_INLINE ushort_t f2bf(float f) {                 // RNE f32 -> bf16 bits
  union { float f; unsigned u; } v; v.f = f;
  unsigned r = v.u + 0x7fffu + ((v.u >> 16) & 1u);
  return (ushort_t)(r >> 16);
}
DEV_INLINE float bf2f(ushort_t s) {
  union { unsigned u; float f; } v; v.u = ((unsigned)s) << 16;
  return v.f;
}
DEV_INLINE float sigmoidf_(float x) {
  return __builtin_amdgcn_rcpf(1.0f + __expf(-x));
}
DEV_INLINE float tanhf_(float x) {                  // 1 - 2/(1+e^{2x}); safe at +-inf
  return 1.0f - 2.0f * __builtin_amdgcn_rcpf(1.0f + __expf(2.0f * x));
}

// async global->LDS, 16B per lane; dst must be wave-uniform base + lane*16.
DEV_INLINE void gload16(const ushort_t* g, ushort_t* l) {
  __builtin_amdgcn_global_load_lds(
      (const __attribute__((address_space(1))) unsigned int*)g,
      (__attribute__((address_space(3))) unsigned int*)l, 16, 0, 0);
}

// --------------------------- weight prep (tiled transpose) ------------------
__global__ __launch_bounds__(256) void k_prep(
    const float* __restrict__ Wih0, const float* __restrict__ Wih1,
    const float* __restrict__ Wih2, const float* __restrict__ Whh0,
    const float* __restrict__ Whh1, const float* __restrict__ Whh2,
    const float* __restrict__ Wout1, const float* __restrict__ Wout2,
    ushort_t* __restrict__ WT)
{
  __shared__ float T[32][65];
  const int b = blockIdx.x;
  const int tid = threadIdx.x;
  const float* S; int Kd, C; size_t dstBase; int kt, nt;
  if (b < 32) {
    int rel = b; int d = (rel >> 3) / 2; kt = (rel >> 3) & 1; nt = rel & 7;
    S = Wih0 + (size_t)d * 64 * 512; C = 512; Kd = 64;
    dstBase = 0 + (size_t)d * 512 * 64;
  } else if (b < 160) {
    int rel = b - 32; int d = (rel >> 3) / 8; kt = (rel >> 3) & 7; nt = rel & 7;
    S = Wih1 + (size_t)d * 256 * 512; C = 512; Kd = 256;
    dstBase = 65536 + (size_t)d * 512 * 256;
  } else if (b < 288) {
    int rel = b - 160; int d = (rel >> 3) / 8; kt = (rel >> 3) & 7; nt = rel & 7;
    S = Wih2 + (size_t)d * 256 * 512; C = 512; Kd = 256;
    dstBase = 327680 + (size_t)d * 512 * 256;
  } else if (b < 352) {
    int rel = b - 288; int d = (rel >> 3) / 4; kt = (rel >> 3) & 3; nt = rel & 7;
    S = Whh0 + (size_t)d * 128 * 512; C = 512; Kd = 128;
    dstBase = 589824 + (size_t)d * 512 * 128;
  } else if (b < 416) {
    int rel = b - 352; int d = (rel >> 3) / 4; kt = (rel >> 3) & 3; nt = rel & 7;
    S = Whh1 + (size_t)d * 128 * 512; C = 512; Kd = 128;
    dstBase = 720896 + (size_t)d * 512 * 128;
  } else if (b < 480) {
    int rel = b - 416; int d = (rel >> 3) / 4; kt = (rel >> 3) & 3; nt = rel & 7;
    S = Whh2 + (size_t)d * 128 * 512; C = 512; Kd = 128;
    dstBase = 851968 + (size_t)d * 512 * 128;
  } else if (b < 672) {
    int rel = b - 480; kt = rel >> 3; nt = rel & 7;
    S = Wout1; C = 512; Kd = 768; dstBase = 983040;
  } else {
    int rel = b - 672; kt = rel >> 2; nt = rel & 3;
    S = Wout2; C = 256; Kd = 512; dstBase = 1376256;
  }
  const int k0 = kt * 32, n0 = nt * 64;
  {
    int kr = tid >> 6;                // 0..3
    int n  = tid & 63;
#pragma unroll
    for (int i = 0; i < 8; i++)
      T[i * 4 + kr][n] = S[(size_t)(k0 + i * 4 + kr) * C + n0 + n];
  }
  __syncthreads();
  {
    int n = tid >> 2;                 // 0..63
    int ko = (tid & 3) * 8;           // 0,8,16,24
    ushort_t pk[8];
#pragma unroll
    for (int j = 0; j < 8; j++) pk[j] = f2bf(T[ko + j][n]);
    *(uint4*)(WT + dstBase + (size_t)(n0 + n) * Kd + k0 + ko) = *(uint4*)pk;
  }
}

// --------------------------- input projection ------------------------------
__global__ __launch_bounds__(256) void k_inproj(
    const float* __restrict__ imu, const float* __restrict__ W_in,
    const float* __restrict__ b_in, ushort_t* __restrict__ act0)
{
  int idx = blockIdx.x * 256 + threadIdx.x;   // 64000*64 exactly
  int j = idx & 63, r = idx >> 6;
  int l = r % 50;
  const float* x = imu + (size_t)r * 6;
  float acc = b_in[j];
#pragma unroll
  for (int d = 0; d < 6; d++) acc += x[d] * W_in[d * 64 + j];
  acc += (l * (1.0f / 49.0f)) * W_in[6 * 64 + j] + W_in[7 * 64 + j]; // t, rate=1
  act0[idx] = f2bf(fmaxf(acc, 0.0f));
}

// --------------------------- xg GEMM (bf16 MFMA, 64x256 tile) ---------------
template <int K>
__global__ __launch_bounds__(256, 3) void k_xg_gemm(
    const ushort_t* __restrict__ X,    // [64000][K] bf16 (m-major)
    const ushort_t* __restrict__ WT,   // [2][512][K] bf16 (n-major)
    const float* __restrict__ bih, const float* __restrict__ bhh, // [2][512]
    ushort_t* __restrict__ xg,         // [dirSlot][2][50][1280][256]
    int dirBase)
{
  __shared__ __align__(16) ushort_t As[2][64 * 32];    //  8 KiB
  __shared__ __align__(16) ushort_t Bs[2][256 * 32];   // 32 KiB
  const int dir = blockIdx.z + dirBase;
  const int gp  = blockIdx.y;
  const int m0  = blockIdx.x * 64;
  const int tid = threadIdx.x;
  const int wave = tid >> 6, lane = tid & 63;
  const int cl = lane & 15, quad = lane >> 4;
  const ushort_t* Wd = WT + ((size_t)dir * 512 + gp * 256) * K;   // 256 rows

  float4v acc[4][2][2];
#pragma unroll
  for (int i = 0; i < 4; i++)
#pragma unroll
    for (int u = 0; u < 2; u++)
#pragma unroll
      for (int q = 0; q < 2; q++) acc[i][u][q] = float4v{0.f, 0.f, 0.f, 0.f};

  const int srow = lane >> 2;         // 0..15
  const int scol = (lane & 3) * 8;    // 0,8,16,24

#define STAGE(buf, kb)                                                        \
  {                                                                           \
    gload16(X + (size_t)(m0 + wave * 16 + srow) * K + (kb) + scol,            \
            &As[buf][wave * 16 * 32] + lane * 8);                             \
    _Pragma("unroll")                                                         \
    for (int j = 0; j < 4; j++)                                               \
      gload16(Wd + (size_t)(wave * 64 + j * 16 + srow) * K + (kb) + scol,     \
              &Bs[buf][(wave * 64 + j * 16) * 32] + lane * 8);                \
  }

  STAGE(0, 0)
  for (int kb = 0; kb < K; kb += 32) {
    const int cur = (kb >> 5) & 1;
    __syncthreads();                  // drains DMA for cur; protects cur^1 reuse
    if (kb + 32 < K) STAGE(cur ^ 1, kb + 32)
    short8 Af[4], Bf[2][2];
#pragma unroll
    for (int i = 0; i < 4; i++)
      Af[i] = *(const short8*)(&As[cur][(i * 16 + cl) * 32 + quad * 8]);
#pragma unroll
    for (int u = 0; u < 2; u++)
#pragma unroll
      for (int q = 0; q < 2; q++)
        Bf[u][q] = *(const short8*)(&Bs[cur][(q * 128 + wave * 32 + u * 16 + cl) * 32 + quad * 8]);
#pragma unroll
    for (int i = 0; i < 4; i++)
#pragma unroll
      for (int u = 0; u < 2; u++)
#pragma unroll
        for (int q = 0; q < 2; q++)
          acc[i][u][q] = __builtin_amdgcn_mfma_f32_16x16x32_bf16(Af[i], Bf[u][q], acc[i][u][q], 0, 0, 0);
  }
#undef STAGE

  ushort_t* outp = xg + (size_t)blockIdx.z * 32768000ull + (size_t)gp * 16384000ull;
  const int gbase = dir * 512 + gp * 256;
#pragma unroll
  for (int u = 0; u < 2; u++) {
    const int hc = wave * 32 + u * 16 + cl;
    float b0 = bih[gbase + hc] + bhh[gbase + hc];
    float b1 = bih[gbase + 128 + hc] + bhh[gbase + 128 + hc];
#pragma unroll
    for (int i = 0; i < 4; i++) {
#pragma unroll
      for (int r = 0; r < 4; r++) {
        int m = m0 + i * 16 + quad * 4 + r;   // D: row=quad*4+r, col=lane&15
        int seq = m / 50, t = m - seq * 50;
        unsigned pk = (unsigned)f2bf(acc[i][u][0][r] + b0) |
                      ((unsigned)f2bf(acc[i][u][1][r] + b1) << 16);
        *(unsigned*)(outp + ((size_t)t * 1280 + seq) * 256 + hc * 2) = pk;
      }
    }
  }
}

// --------------------------- LSTM scan (round 5) ----------------------------
// One block = 16 seqs of one direction, 1024 thr / 16 waves.
// Phase 1: wave (gp=w>>3, hg=w&7) computes gates {gp*2, gp*2+1} for hcols
//          hg*16+cl via 8 MFMAs (Whh frags in VGPRs); writes pre-activation
//          sums to LDS P{gp} (float2, 2-way-free b64). Also issues next
//          step's x loads into VGPRs and flushes pending Y stores.
// Phase 2: 2048 cells / 1024 lanes = 2 cells each: read P0/P1 + x regs,
//          LSTM pointwise (fp32), write h (bf16) to hbuf.
// MODE 0: write Y. MODE 1: fused mean/max/final aggregation (bf16 agg).
template <int MODE>
__global__ __launch_bounds__(1024, 1) void k_scan(
    const ushort_t* __restrict__ xg,    // [dirSlot][2][50][1280][256]
    const ushort_t* __restrict__ WhhT,  // [2][512][128] bf16 n-major
    ushort_t* __restrict__ Y,           // [64000][256] bf16
    ushort_t* __restrict__ aggb,        // [1280][768] bf16
    int dirBase)
{
  const int dir = blockIdx.y + dirBase;
  const int s0 = blockIdx.x * 16;
  const int tid = threadIdx.x;
  const int wave = tid >> 6, lane = tid & 63;
  const int cl = lane & 15, quad = lane >> 4;
  const int gp = wave >> 3;             // gate pair: 0=(i,f) 1=(g,o)
  const int hcolw = (wave & 7) * 16 + cl;

  __shared__ __align__(16) ushort_t hbuf[2][16][136];   // 8.5 KiB
  __shared__ __align__(16) float P0[2048 * 2];          // 16 KiB (i,f sums)
  __shared__ __align__(16) float P1[2048 * 2];          // 16 KiB (g,o sums)

  // Whh^T fragments for this wave's 2 gates: 2 x 4 x short8 = 32 VGPR
  short8 Bf[2][4];
  const ushort_t* WTd = WhhT + (size_t)dir * (512 * 128);
#pragma unroll
  for (int q = 0; q < 2; q++)
#pragma unroll
    for (int kt = 0; kt < 4; kt++)
      Bf[q][kt] = *(const short8*)(WTd + ((gp * 2 + q) * 128 + hcolw) * 128 + kt * 32 + quad * 8);

  // per-lane pointwise cells: c = tid + j*1024
  int cseq[2], chcol[2];
#pragma unroll
  for (int j = 0; j < 2; j++) { int c = tid + j * 1024; cseq[j] = c >> 7; chcol[j] = c & 127; }

  float cst[2] = {0.f, 0.f};
  float sum[2] = {0.f, 0.f};
  float mx[2]  = {-3.0e38f, -3.0e38f};
  float hLast[2] = {0.f, 0.f};
  ushort_t pend[2] = {0, 0};
  int tPrev = 0;

  for (int i = tid; i < 16 * 136; i += 1024) ((ushort_t*)hbuf[0])[i] = 0;

  const ushort_t* xgp = xg + (size_t)blockIdx.y * 32768000ull;
  const int t0 = dir ? 49 : 0;

  unsigned xifC[2], xgoC[2], xifN[2], xgoN[2];
#pragma unroll
  for (int j = 0; j < 2; j++) {
    size_t base = ((size_t)t0 * 1280 + s0 + cseq[j]) * 256 + chcol[j] * 2;
    xifC[j] = *(const unsigned*)(xgp + base);
    xgoC[j] = *(const unsigned*)(xgp + 16384000u + base);
  }
  __syncthreads();                      // hbuf zero visible

  for (int step = 0; step < 50; step++) {
    const int t = dir ? (49 - step) : step;
    const int cur = step & 1;

    // ---- phase 1 ----
    if (step < 49) {                    // next step's x -> VGPRs (no LDS, no drain)
      const int tn = dir ? (t - 1) : (t + 1);
#pragma unroll
      for (int j = 0; j < 2; j++) {
        size_t base = ((size_t)tn * 1280 + s0 + cseq[j]) * 256 + chcol[j] * 2;
        xifN[j] = *(const unsigned*)(xgp + base);
        xgoN[j] = *(const unsigned*)(xgp + 16384000u + base);
      }
    }
    if (MODE == 0 && step > 0) {        // flush previous step's Y
#pragma unroll
      for (int j = 0; j < 2; j++)
        Y[((size_t)(s0 + cseq[j]) * 50 + tPrev) * 256 + dir * 128 + chcol[j]] = pend[j];
    }

    short8 Af[4];
#pragma unroll
    for (int kt = 0; kt < 4; kt++)      // A: m=lane&15, k=quad*8+j
      Af[kt] = *(const short8*)(&hbuf[cur][cl][kt * 32 + quad * 8]);

    float4v acc[2];
#pragma unroll
    for (int q = 0; q < 2; q++) acc[q] = float4v{0.f, 0.f, 0.f, 0.f};
#pragma unroll
    for (int kt = 0; kt < 4; kt++)
#pragma unroll
      for (int q = 0; q < 2; q++)
        acc[q] = __builtin_amdgcn_mfma_f32_16x16x32_bf16(Af[kt], Bf[q][kt], acc[q], 0, 0, 0);

    float* Pg = gp ? P1 : P0;
#pragma unroll
    for (int r = 0; r < 4; r++) {
      int cell = (quad * 4 + r) * 128 + hcolw;
      *(float2*)(Pg + cell * 2) = make_float2(acc[0][r], acc[1][r]);
    }
    __syncthreads();                    // gate sums visible

    // ---- phase 2 ----
#pragma unroll
    for (int j = 0; j < 2; j++) {
      int c = tid + j * 1024;
      float2 a0 = *(const float2*)(P0 + c * 2);
      float2 a1 = *(const float2*)(P1 + c * 2);
      float gi = a0.x + bf2f((ushort_t)(xifC[j] & 0xffff));
      float gf = a0.y + bf2f((ushort_t)(xifC[j] >> 16));
      float gg = a1.x + bf2f((ushort_t)(xgoC[j] & 0xffff));
      float go = a1.y + bf2f((ushort_t)(xgoC[j] >> 16));
      float ii = sigmoidf_(gi);
      float ff = sigmoidf_(gf);
      float gc = tanhf_(gg);
      float oo = sigmoidf_(go);
      float c2 = ff * cst[j] + ii * gc;
      cst[j] = c2;
      float h = oo * tanhf_(c2);
      ushort_t hb = f2bf(h);
      hbuf[cur ^ 1][cseq[j]][chcol[j]] = hb;
      if (MODE == 0) {
        pend[j] = hb;
      } else {
        sum[j] += h;
        mx[j] = fmaxf(mx[j], h);
        hLast[j] = h;
      }
    }
    tPrev = t;
    __syncthreads();                    // h visible; P reusable
#pragma unroll
    for (int j = 0; j < 2; j++) { xifC[j] = xifN[j]; xgoC[j] = xgoN[j]; }
  }

  if (MODE == 0) {
#pragma unroll
    for (int j = 0; j < 2; j++)
      Y[((size_t)(s0 + cseq[j]) * 50 + tPrev) * 256 + dir * 128 + chcol[j]] = pend[j];
  } else {
#pragma unroll
    for (int j = 0; j < 2; j++) {
      const int seq = s0 + cseq[j];
      const int c = dir * 128 + chcol[j];
      aggb[(size_t)seq * 768 + c]       = f2bf(sum[j] * (1.0f / 50.0f));
      aggb[(size_t)seq * 768 + 256 + c] = f2bf(mx[j]);
      aggb[(size_t)seq * 768 + 512 + c] = f2bf(hLast[j]);   // h_n of this dir
    }
  }
}

// --------------------------- fused head -------------------------------------
__global__ __launch_bounds__(512, 1) void k_head(
    const ushort_t* __restrict__ aggb,  // [1280][768] bf16
    const ushort_t* __restrict__ W1T,   // [512][768] bf16
    const float* __restrict__ b1, const float* __restrict__ ln_g,
    const float* __restrict__ ln_b,
    const ushort_t* __restrict__ W2T,   // [256][512] bf16
    const float* __restrict__ b2, float* __restrict__ out) // [1280][256]
{
  __shared__ __align__(16) char smem[78336];
  ushort_t* AsB = (ushort_t*)smem;            // [2][64*32]   (8 KiB)
  ushort_t* BsB = (ushort_t*)(smem + 8192);   // [2][512*32]  (64 KiB)
  ushort_t* hn  = (ushort_t*)smem;            // [64][520] aliased (66.6 KiB)
  float* partS  = (float*)(smem + 73728);     // [64][8]
  float* partQ  = partS + 512;                // [64][8]
  float* muS    = partQ + 512;                // [64]
  float* rsS    = muS + 64;                   // [64]

  const int m0 = blockIdx.x * 64;
  const int tid = threadIdx.x;
  const int wave = tid >> 6, lane = tid & 63;
  const int cl = lane & 15, quad = lane >> 4;
  const int srow = lane >> 2, scol = (lane & 3) * 8;

  float4v acc1[4][4];
#pragma unroll
  for (int i = 0; i < 4; i++)
#pragma unroll
    for (int v = 0; v < 4; v++) acc1[i][v] = float4v{0.f, 0.f, 0.f, 0.f};

#define STAGE1(buf, kb)                                                       \
  {                                                                           \
    if (wave < 4)                                                             \
      gload16(aggb + (size_t)(m0 + wave * 16 + srow) * 768 + (kb) + scol,     \
              AsB + (buf) * 2048 + wave * 16 * 32 + lane * 8);                \
    _Pragma("unroll")                                                         \
    for (int j = 0; j < 4; j++)                                               \
      gload16(W1T + (size_t)(wave * 64 + j * 16 + srow) * 768 + (kb) + scol,  \
              BsB + (buf) * 16384 + (wave * 64 + j * 16) * 32 + lane * 8);    \
  }

  STAGE1(0, 0)
  for (int kb = 0; kb < 768; kb += 32) {
    const int cur = (kb >> 5) & 1;
    __syncthreads();
    if (kb + 32 < 768) STAGE1(cur ^ 1, kb + 32)
    short8 Af[4], Bf[4];
#pragma unroll
    for (int i = 0; i < 4; i++)
      Af[i] = *(const short8*)(AsB + cur * 2048 + (i * 16 + cl) * 32 + quad * 8);
#pragma unroll
    for (int v = 0; v < 4; v++)
      Bf[v] = *(const short8*)(BsB + cur * 16384 + (wave * 64 + v * 16 + cl) * 32 + quad * 8);
#pragma unroll
    for (int i = 0; i < 4; i++)
#pragma unroll
      for (int v = 0; v < 4; v++)
        acc1[i][v] = __builtin_amdgcn_mfma_f32_16x16x32_bf16(Af[i], Bf[v], acc1[i][v], 0, 0, 0);
  }
#undef STAGE1
  __syncthreads();          // all waves done with AsB/BsB (hn aliases them)

  float bcol[4], lg[4], lb[4];
#pragma unroll
  for (int v = 0; v < 4; v++) {
    int col = wave * 64 + v * 16 + cl;
    bcol[v] = b1[col]; lg[v] = ln_g[col]; lb[v] = ln_b[col];
  }

#pragma unroll
  for (int i = 0; i < 4; i++) {
#pragma unroll
    for (int r = 0; r < 4; r++) {
      float s = 0.f, q = 0.f;
#pragma unroll
      for (int v = 0; v < 4; v++) {
        float x = acc1[i][v][r] + bcol[v];
        s += x; q += x * x;
      }
#pragma unroll
      for (int m = 1; m <= 8; m <<= 1) {
        s += __shfl_xor(s, m);
        q += __shfl_xor(q, m);
      }
      if (cl == 0) {
        int row = i * 16 + quad * 4 + r;
        partS[row * 8 + wave] = s;
        partQ[row * 8 + wave] = q;
      }
    }
  }
  __syncthreads();
  if (tid < 64) {
    float s = 0.f, q = 0.f;
#pragma unroll
    for (int w = 0; w < 8; w++) { s += partS[tid * 8 + w]; q += partQ[tid * 8 + w]; }
    float mu = s * (1.0f / 512.0f);
    float var = q * (1.0f / 512.0f) - mu * mu;
    muS[tid] = mu;
    rsS[tid] = rsqrtf(var + 1e-5f);
  }
  __syncthreads();

#pragma unroll
  for (int i = 0; i < 4; i++) {
#pragma unroll
    for (int r = 0; r < 4; r++) {
      int row = i * 16 + quad * 4 + r;
      float mu = muS[row], rs = rsS[row];
#pragma unroll
      for (int v = 0; v < 4; v++) {
        int col = wave * 64 + v * 16 + cl;
        float x = acc1[i][v][r] + bcol[v];
        float y = (x - mu) * rs * lg[v] + lb[v];
        hn[row * 520 + col] = f2bf(fmaxf(y, 0.0f));
      }
    }
  }
  __syncthreads();

  float4v acc2[4][2];
#pragma unroll
  for (int i = 0; i < 4; i++)
#pragma unroll
    for (int u = 0; u < 2; u++) acc2[i][u] = float4v{0.f, 0.f, 0.f, 0.f};
  for (int kt = 0; kt < 16; kt++) {
    short8 Af2[4], Bf2[2];
#pragma unroll
    for (int u = 0; u < 2; u++)
      Bf2[u] = *(const short8*)(W2T + (size_t)(wave * 32 + u * 16 + cl) * 512 + kt * 32 + quad * 8);
#pragma unroll
    for (int i = 0; i < 4; i++)
      Af2[i] = *(const short8*)(hn + (i * 16 + cl) * 520 + kt * 32 + quad * 8);
#pragma unroll
    for (int i = 0; i < 4; i++)
#pragma unroll
      for (int u = 0; u < 2; u++)
        acc2[i][u] = __builtin_amdgcn_mfma_f32_16x16x32_bf16(Af2[i], Bf2[u], acc2[i][u], 0, 0, 0);
  }
#pragma unroll
  for (int u = 0; u < 2; u++) {
    int col = wave * 32 + u * 16 + cl;
    float bb = b2[col];
#pragma unroll
    for (int i = 0; i < 4; i++)
#pragma unroll
      for (int r = 0; r < 4; r++)
        out[(size_t)(m0 + i * 16 + quad * 4 + r) * 256 + col] = acc2[i][u][r] + bb;
  }
}

// --------------------------- launcher --------------------------------------
extern "C" void kernel_launch(void* const* d_in, const int* in_sizes, int n_in,
                              void* d_out, int out_size, void* d_ws, size_t ws_size,
                              hipStream_t stream)
{
  (void)in_sizes; (void)n_in; (void)out_size;
  const float* imu   = (const float*)d_in[0];
  const float* W_in  = (const float*)d_in[1];
  const float* b_in  = (const float*)d_in[2];
  const float* Wih0  = (const float*)d_in[3];
  const float* Whh0  = (const float*)d_in[4];
  const float* bih0  = (const float*)d_in[5];
  const float* bhh0  = (const float*)d_in[6];
  const float* Wih1  = (const float*)d_in[7];
  const float* Whh1  = (const float*)d_in[8];
  const float* bih1  = (const float*)d_in[9];
  const float* bhh1  = (const float*)d_in[10];
  const float* Wih2  = (const float*)d_in[11];
  const float* Whh2  = (const float*)d_in[12];
  const float* bih2  = (const float*)d_in[13];
  const float* bhh2  = (const float*)d_in[14];
  const float* Wout1 = (const float*)d_in[15];
  const float* bout1 = (const float*)d_in[16];
  const float* ln_g  = (const float*)d_in[17];
  const float* ln_b  = (const float*)d_in[18];
  const float* Wout2 = (const float*)d_in[19];
  const float* bout2 = (const float*)d_in[20];
  float* out = (float*)d_out;
  char* ws = (char*)d_ws;

  // ws layout (bytes)
  const size_t ACT0_OFF = 0;                      // 8,192,000  (64000*64*2)
  const size_t YA_OFF   = 8192000;                // 32,768,000 (64000*256*2)
  const size_t YB_OFF   = 40960000;               // 32,768,000
  const size_t XG_OFF   = 73728000;               // 131,072,000 (both) / 65,536,000 (serial)
  const size_t XG_BOTH  = 131072000, XG_SER = 65536000;
  const size_t WT_SZ    = 3014656;                // 1,507,328 bf16 elems
  const bool both = ws_size >= XG_OFF + XG_BOTH + WT_SZ;
  const size_t WT_OFF = XG_OFF + (both ? XG_BOTH : XG_SER);

  ushort_t* act0 = (ushort_t*)(ws + ACT0_OFF);
  ushort_t* Ya   = (ushort_t*)(ws + YA_OFF);
  ushort_t* Yb   = (ushort_t*)(ws + YB_OFF);
  ushort_t* xg   = (ushort_t*)(ws + XG_OFF);
  ushort_t* WT   = (ushort_t*)(ws + WT_OFF);
  ushort_t* aggb = (ushort_t*)(ws + 0);           // reuses act0 region (dead by then)

  ushort_t* WT_ih0 = WT + 0;
  ushort_t* WT_ih1 = WT + 65536;
  ushort_t* WT_ih2 = WT + 327680;
  ushort_t* WT_hh0 = WT + 589824;
  ushort_t* WT_hh1 = WT + 720896;
  ushort_t* WT_hh2 = WT + 851968;
  ushort_t* W1T    = WT + 983040;
  ushort_t* W2T    = WT + 1376256;

  k_prep<<<736, 256, 0, stream>>>(Wih0, Wih1, Wih2, Whh0, Whh1, Whh2,
                                  Wout1, Wout2, WT);
  k_inproj<<<16000, 256, 0, stream>>>(imu, W_in, b_in, act0);

  const int nPass = both ? 1 : 2;
  const int gz = both ? 2 : 1;

  const ushort_t* Xs[3]   = {act0, Ya, Yb};
  ushort_t* Ys[3]         = {Ya, Yb, Ya};
  const ushort_t* WTih[3] = {WT_ih0, WT_ih1, WT_ih2};
  const ushort_t* WThh[3] = {WT_hh0, WT_hh1, WT_hh2};
  const float* bihs[3]    = {bih0, bih1, bih2};
  const float* bhhs[3]    = {bhh0, bhh1, bhh2};

  for (int layer = 0; layer < 3; layer++) {
    for (int p = 0; p < nPass; p++) {
      int dirBase = both ? 0 : p;
      if (layer == 0)
        k_xg_gemm<64><<<dim3(1000, 2, gz), 256, 0, stream>>>(
            Xs[0], WTih[0], bihs[0], bhhs[0], xg, dirBase);
      else
        k_xg_gemm<256><<<dim3(1000, 2, gz), 256, 0, stream>>>(
            Xs[layer], WTih[layer], bihs[layer], bhhs[layer], xg, dirBase);
      if (layer < 2)
        k_scan<0><<<dim3(80, gz), 1024, 0, stream>>>(xg, WThh[layer], Ys[layer], aggb, dirBase);
      else
        k_scan<1><<<dim3(80, gz), 1024, 0, stream>>>(xg, WThh[layer], Ys[layer], aggb, dirBase);
    }
  }

  k_head<<<20, 512, 0, stream>>>(aggb, W1T, bout1, ln_g, ln_b, W2T, bout2, out);
}